// Round 15
// baseline (622.033 us; speedup 1.0000x reference)
//
#include <hip/hip_runtime.h>
#include <hip/hip_bf16.h>
#include <math.h>

typedef __hip_bfloat16 bf16;
typedef __attribute__((ext_vector_type(8))) short short8v;    // 8 bf16 (4 VGPRs)
typedef __attribute__((ext_vector_type(4))) float float4v;    // 16x16 accumulator
typedef __attribute__((ext_vector_type(16))) float float16v;  // 32x32 accumulator

static constexpr int kB = 32;
static constexpr int kP = 192;
static constexpr int kS = 36;
static constexpr int kC = 64;
static constexpr int kRows = kB * kP;   // 6144
static constexpr float kPI = 3.14159265358979323846f;

__device__ __constant__ int d_SX[36] = {
  0,2,4,6,8,10,12,14,16,18,20,22,24,26,28,30,32,34,
  36,38,40,42,44,46,48,50,52,54,56,58,60,62,64,66,68,71};

__device__ __forceinline__ float b2f(bf16 v) { return __bfloat162float(v); }
__device__ __forceinline__ unsigned short f2bu(float f) {
  bf16 h = __float2bfloat16(f);
  return *reinterpret_cast<unsigned short*>(&h);
}
__device__ __forceinline__ float su2f(unsigned short u) {
  bf16 t; *reinterpret_cast<unsigned short*>(&t) = u; return __bfloat162float(t);
}
#define MFMA16 __builtin_amdgcn_mfma_f32_16x16x32_bf16
#define MFMA32 __builtin_amdgcn_mfma_f32_32x32x16_bf16

// ---- conv weight prep (16x16 frag): (CO=64, CI, 9) f32 -> [t][chi][wid][lane][8] ----
__global__ __launch_bounds__(256) void k_wprep(
    const float* __restrict__ src, bf16* __restrict__ dst, int CI, int total)
{
  int d = blockIdx.x * 256 + threadIdx.x;
  if (d >= total) return;
  int j   = d & 7;
  int l   = (d >> 3) & 63;
  int wid = (d >> 9) & 3;
  int r   = d >> 11;
  int nchi = CI >> 5;
  int chi = r % nchi, t = r / nchi;
  int co = wid * 16 + (l & 15);
  int ci = chi * 32 + 8 * (l >> 4) + j;
  dst[d] = __float2bfloat16(src[(co * CI + ci) * 9 + t]);
}

// ---- conv weight prep (32x32 frag): (CO=64, CI, 9) f32 -> [t][chi16][ct2][lane][8] ----
// co = ct*32 + (l&31); ci = chi16*16 + 8*(l>>5) + j
__global__ __launch_bounds__(256) void k_wprep32(
    const float* __restrict__ src, bf16* __restrict__ dst, int CI, int total)
{
  int d = blockIdx.x * 256 + threadIdx.x;
  if (d >= total) return;
  int j  = d & 7;
  int l  = (d >> 3) & 63;
  int ct = (d >> 9) & 1;
  int r  = d >> 10;
  int nchi = CI >> 4;
  int chi = r % nchi, t = r / nchi;
  int co = ct * 32 + (l & 31);
  int ci = chi * 16 + 8 * (l >> 5) + j;
  dst[d] = __float2bfloat16(src[(co * CI + ci) * 9 + t]);
}

// ---- fc weight prep: fc_w (2304=c*36+s, 64) f32 -> [72][4][64][8] bf16 ----
__global__ __launch_bounds__(256) void k_wprep_fc(
    const float* __restrict__ src, bf16* __restrict__ dst)
{
  int d = blockIdx.x * 256 + threadIdx.x;
  if (d >= 2304 * 64) return;
  int j    = d & 7;
  int l    = (d >> 3) & 63;
  int tile = (d >> 9) & 3;
  int kk   = d >> 11;
  int cout = tile * 16 + (l & 15);
  int k    = kk * 32 + 8 * (l >> 4) + j;    // = s*64 + c
  int c = k & 63, s = k >> 6;
  dst[d] = __float2bfloat16(src[(c * kS + s) * kC + cout]);
}

// ---- mlp_w (cin,cout) f32 -> mlpwT [cout][cin] bf16 ----
__global__ __launch_bounds__(256) void k_wprep_mlpT(
    const float* __restrict__ src, bf16* __restrict__ dst)
{
  int d = blockIdx.x * 256 + threadIdx.x;
  if (d >= 64 * 64) return;
  int co = d >> 6, ci = d & 63;
  dst[d] = __float2bfloat16(src[ci * 64 + co]);
}

// ---- reg_w (64,76) + cls_w (64,2) -> rcT [80][64] bf16 ; biases -> rcb[80] f32 ----
__global__ __launch_bounds__(256) void k_wprep_rct(
    const float* __restrict__ regw, const float* __restrict__ clsw,
    const float* __restrict__ regb, const float* __restrict__ clsb,
    bf16* __restrict__ dst, float* __restrict__ rcb)
{
  int d = blockIdx.x * 256 + threadIdx.x;
  if (d < 80 * 64) {
    int o = d >> 6, ci = d & 63;
    float v = (o < 76) ? regw[ci * 76 + o] : (o < 78 ? clsw[ci * 2 + (o - 76)] : 0.f);
    dst[d] = __float2bfloat16(v);
  }
  if (d < 80) rcb[d] = (d < 76) ? regb[d] : (d < 78 ? clsb[d - 76] : 0.f);
}

// ---- fmap transpose: [b][c][h][w] f32 -> [b][y][x][c] bf16 ----
__global__ __launch_bounds__(256) void k_transpose(
    const float* __restrict__ src, bf16* __restrict__ dst, int h, int w)
{
  __shared__ float tile[64][65];
  const int by = blockIdx.x;        // b*h + y
  const int b = by / h, y = by % h;
  const int lane = threadIdx.x & 63, wq = threadIdx.x >> 6;
  for (int x0 = 0; x0 < w; x0 += 64) {
    #pragma unroll
    for (int cc = 0; cc < 16; ++cc) {
      int c = wq * 16 + cc;
      int x = x0 + lane;
      if (x < w) tile[c][lane] = src[((size_t)(b*kC + c)*h + y)*w + x];
    }
    __syncthreads();
    #pragma unroll
    for (int xx = 0; xx < 16; ++xx) {
      int x = x0 + wq * 16 + xx;
      if (x < w) dst[((size_t)(b*h + y)*w + x)*kC + lane] = __float2bfloat16(tile[lane][wq*16 + xx]);
    }
    __syncthreads();
  }
}

// ---- fused grid_sample + conv1d(k9,pad4) MFMA + BN + ReLU ; 2 rows/block (r14-proven) ----
__global__ __launch_bounds__(256) void k_trans(
    const bf16* __restrict__ fmapT, int h, int w,
    const float* __restrict__ pfeat0, const float* __restrict__ pfeatw, int stage,
    const bf16* __restrict__ wfrag,     // fragment-linear [9][2][4][64][8]
    const float* __restrict__ bnp,      // (4,64) f32
    bf16* __restrict__ transOut)        // (6144,36,64) bf16
{
  __shared__ __align__(16) bf16 poolT[2][56][64];
  __shared__ float bsc[kC], bsh[kC];
  const int tid = threadIdx.x;
  const int row0 = blockIdx.x * 2, b = row0 / kP;

  if (tid < kC) {
    float g = bnp[tid], bb = bnp[kC + tid];
    float m = bnp[2*kC + tid], v = bnp[3*kC + tid];
    float sc = g / sqrtf(v + 1e-5f);
    bsc[tid] = sc; bsh[tid] = bb - m * sc;
  }
  unsigned int* pz = (unsigned int*)&poolT[0][0][0];
  for (int e = tid; e < 2*56*32; e += 256) pz[e] = 0u;
  __syncthreads();

  const int lc = tid & 7;
  for (int idx = tid >> 3; idx < 2*kS; idx += 32) {
    int r2 = idx / kS, s = idx % kS;
    int row = row0 + r2, p = row % kP;
    float px = (stage == 0) ? pfeat0[p*kS + (kS-1-s)] : pfeatw[row*kS + (kS-1-s)];
    float fy = 1.0f - (float)d_SX[kS-1-s] / 71.0f;
    float x = px * (float)(w - 1);
    float y = fy * (float)(h - 1);
    float x0f = floorf(x), y0f = floorf(y);
    float wx = x - x0f, wy = y - y0f;
    int xi = (int)x0f, yi = (int)y0f;
    float a8[8];
    #pragma unroll
    for (int j = 0; j < 8; ++j) a8[j] = 0.f;
    #pragma unroll
    for (int cy = 0; cy < 2; ++cy) {
      #pragma unroll
      for (int cx = 0; cx < 2; ++cx) {
        int xx = xi + cx, yy = yi + cy;
        if (xx >= 0 && xx < w && yy >= 0 && yy < h) {
          float wgt = (cx ? wx : 1.f - wx) * (cy ? wy : 1.f - wy);
          short8v v = *(const short8v*)&fmapT[((size_t)(b*h + yy)*w + xx)*kC + lc*8];
          #pragma unroll
          for (int j = 0; j < 8; ++j)
            a8[j] += su2f((unsigned short)v[j]) * wgt;
        }
      }
    }
    uint4 pk;
    pk.x = (unsigned)f2bu(a8[0]) | ((unsigned)f2bu(a8[1]) << 16);
    pk.y = (unsigned)f2bu(a8[2]) | ((unsigned)f2bu(a8[3]) << 16);
    pk.z = (unsigned)f2bu(a8[4]) | ((unsigned)f2bu(a8[5]) << 16);
    pk.w = (unsigned)f2bu(a8[6]) | ((unsigned)f2bu(a8[7]) << 16);
    int lr = s + 4;
    *reinterpret_cast<uint4*>(&poolT[r2][lr][((lc + lr) & 7)*8]) = pk;
  }
  __syncthreads();

  const int wv = tid >> 6, lane = tid & 63;
  const int r2 = wv & 1, cp = wv >> 1;    // wave = (row, cout-pair)
  const int lm = lane & 15, lq = lane >> 4;
  float4v acc[2][3] = {{{0,0,0,0},{0,0,0,0},{0,0,0,0}},{{0,0,0,0},{0,0,0,0},{0,0,0,0}}};
  #pragma unroll
  for (int t = 0; t < 9; ++t) {
    #pragma unroll
    for (int chi = 0; chi < 2; ++chi) {
      short8v a0 = *(const short8v*)&wfrag[(((t*2 + chi)*4 + cp*2 + 0)*64 + lane)*8];
      short8v a1 = *(const short8v*)&wfrag[(((t*2 + chi)*4 + cp*2 + 1)*64 + lane)*8];
      #pragma unroll
      for (int nt = 0; nt < 3; ++nt) {
        int rr = nt*16 + lm + t;
        int sl = chi*4 + lq;
        short8v bb = *(const short8v*)&poolT[r2][rr][((sl + rr) & 7)*8];
        acc[0][nt] = MFMA16(a0, bb, acc[0][nt], 0, 0, 0);
        acc[1][nt] = MFMA16(a1, bb, acc[1][nt], 0, 0, 0);
      }
    }
  }
  #pragma unroll
  for (int c2 = 0; c2 < 2; ++c2) {
    const int c4 = (cp*2 + c2)*16 + 4*lq;
    float s0 = bsc[c4], s1 = bsc[c4+1], s2 = bsc[c4+2], s3 = bsc[c4+3];
    float h0 = bsh[c4], h1 = bsh[c4+1], h2 = bsh[c4+2], h3 = bsh[c4+3];
    #pragma unroll
    for (int nt = 0; nt < 3; ++nt) {
      int s = nt*16 + lm;
      if (s < kS) {
        uint2 pk;
        pk.x = (unsigned)f2bu(fmaxf(acc[c2][nt][0]*s0 + h0, 0.f))
             | ((unsigned)f2bu(fmaxf(acc[c2][nt][1]*s1 + h1, 0.f)) << 16);
        pk.y = (unsigned)f2bu(fmaxf(acc[c2][nt][2]*s2 + h2, 0.f))
             | ((unsigned)f2bu(fmaxf(acc[c2][nt][3]*s3 + h3, 0.f)) << 16);
        *reinterpret_cast<uint2*>(&transOut[((size_t)(row0+r2)*kS + s)*kC + c4]) = pk;
      }
    }
  }
}

// ---- concat conv via 32x32x16 MFMA; 8 rows/block, 192 thr = 3 waves, 3 M-tiles/wave ----
// M = 8*36 = 288 = EXACTLY 9 tiles of 32 (r12 bug fixed: full coverage).
// per k-step: 3 ds_reads + 2 A-loads -> 6 MFMA32 ; chunked K (64 ch), 0-conflict swizzle
template<int NCHUNK>
__global__ __launch_bounds__(192) void k_catconv32(
    const bf16* __restrict__ t0, const bf16* __restrict__ t1, const bf16* __restrict__ t2,
    const bf16* __restrict__ wfrag,   // [9][NCHUNK*4][2][64][8]
    const float* __restrict__ bnp, bf16* __restrict__ catOut)
{
  constexpr int NCHI16 = NCHUNK * 4;
  __shared__ __align__(16) bf16 chunk[352][64];   // 8 rows x 44 padded positions
  __shared__ float bsc[kC], bsh[kC];
  const int tid = threadIdx.x;
  const int row0 = blockIdx.x * 8;
  if (tid < kC) {
    float g = bnp[tid], bb = bnp[kC + tid];
    float m = bnp[2*kC + tid], v = bnp[3*kC + tid];
    float sc = g / sqrtf(v + 1e-5f);
    bsc[tid] = sc; bsh[tid] = bb - m * sc;
  }
  const bf16* tb[3] = {t0, t1, t2};

  const int wv = tid / 64, lane = tid & 63;
  const int l5 = lane >> 5, l31 = lane & 31;
  int baseR[3], rA[3], sA[3];
  #pragma unroll
  for (int i = 0; i < 3; ++i) {
    int m = (3*wv + i)*32 + l31;
    rA[i] = m / kS; sA[i] = m % kS;
    baseR[i] = rA[i]*44 + sA[i];
  }
  float16v acc[3][2];
  #pragma unroll
  for (int i = 0; i < 3; ++i)
    #pragma unroll
    for (int ct = 0; ct < 2; ++ct)
      #pragma unroll
      for (int r = 0; r < 16; ++r) acc[i][ct][r] = 0.f;

  #pragma unroll
  for (int kc = 0; kc < NCHUNK; ++kc) {
    if (kc > 0) __syncthreads();
    // stage 64-channel chunk of trans[kc] for 8 roi rows, swizzled (zeros in pads)
    for (int e = tid; e < 352*8; e += 192) {
      int lr = e >> 3, slot = e & 7;
      int rr = lr / 44, sp = lr % 44;
      short8v v = {0,0,0,0,0,0,0,0};
      if (sp >= 4 && sp < 40)
        v = *(const short8v*)&tb[kc][((size_t)(row0 + rr)*kS + (sp - 4))*kC + slot*8];
      *(short8v*)&chunk[lr][((slot + lr) & 7)*8] = v;
    }
    __syncthreads();
    #pragma unroll
    for (int t = 0; t < 9; ++t) {
      #pragma unroll
      for (int ks = 0; ks < 4; ++ks) {        // chi16 within chunk
        int slot = ks*2 + l5;
        short8v bfrag[3];
        #pragma unroll
        for (int i = 0; i < 3; ++i) {
          int rr = baseR[i] + t;
          bfrag[i] = *(const short8v*)&chunk[rr][((slot + rr) & 7)*8];
        }
        int chig = kc*4 + ks;
        #pragma unroll
        for (int ct = 0; ct < 2; ++ct) {
          short8v a = *(const short8v*)&wfrag[(((t*NCHI16 + chig)*2 + ct)*64 + lane)*8];
          acc[0][ct] = MFMA32(a, bfrag[0], acc[0][ct], 0, 0, 0);
          acc[1][ct] = MFMA32(a, bfrag[1], acc[1][ct], 0, 0, 0);
          acc[2][ct] = MFMA32(a, bfrag[2], acc[2][ct], 0, 0, 0);
        }
      }
    }
  }

  // epilogue: C/D layout col=lane&31 (position), row=(reg&3)+8*(reg>>2)+4*(lane>>5) (cout)
  #pragma unroll
  for (int i = 0; i < 3; ++i) {
    bf16* ob = catOut + ((size_t)(row0 + rA[i])*kS + sA[i])*kC;
    #pragma unroll
    for (int ct = 0; ct < 2; ++ct) {
      #pragma unroll
      for (int g = 0; g < 4; ++g) {
        int cb = ct*32 + 8*g + 4*l5;
        float s0 = bsc[cb], s1 = bsc[cb+1], s2 = bsc[cb+2], s3 = bsc[cb+3];
        float h0 = bsh[cb], h1 = bsh[cb+1], h2 = bsh[cb+2], h3 = bsh[cb+3];
        uint2 pk;
        pk.x = (unsigned)f2bu(fmaxf(acc[i][ct][4*g+0]*s0 + h0, 0.f))
             | ((unsigned)f2bu(fmaxf(acc[i][ct][4*g+1]*s1 + h1, 0.f)) << 16);
        pk.y = (unsigned)f2bu(fmaxf(acc[i][ct][4*g+2]*s2 + h2, 0.f))
             | ((unsigned)f2bu(fmaxf(acc[i][ct][4*g+3]*s3 + h3, 0.f)) << 16);
        *reinterpret_cast<uint2*>(&ob[cb]) = pk;
      }
    }
  }
}

// ---- key/value at 250 resize positions; key -> [b][pos256][c], val -> [b][c][pos256] ----
__global__ __launch_bounds__(64) void k_keyval(
    const float* __restrict__ fmap, int h, int w,
    const float* __restrict__ fkeyw, const float* __restrict__ bnk,
    const float* __restrict__ fvalw, const float* __restrict__ fvalb,
    bf16* __restrict__ key_pc, bf16* __restrict__ val_ck)
{
  const int tid = threadIdx.x;
  const int blk = blockIdx.x, b = blk >> 8, pos = blk & 255;
  if (pos >= 250) {
    key_pc[((size_t)b*256 + pos)*kC + tid] = __float2bfloat16(0.f);
    val_ck[((size_t)b*kC + tid)*256 + pos] = __float2bfloat16(0.f);
    return;
  }
  const int i = pos / 25, j = pos % 25;
  const int yi = (i * h) / 10, xj = (j * w) / 25;
  __shared__ float fv[kC];
  fv[tid] = fmap[((size_t)(b*kC + tid) * h + yi) * w + xj];
  __syncthreads();
  float ka = 0.f, va = 0.f;
  const float* kr = fkeyw + tid * kC;
  const float* vr = fvalw + tid * kC;
  for (int c = 0; c < kC; ++c) { float f = fv[c]; ka += f * kr[c]; va += f * vr[c]; }
  float g = bnk[tid], bb = bnk[kC + tid];
  float m = bnk[2*kC + tid], v = bnk[3*kC + tid];
  float sc = g / sqrtf(v + 1e-5f), sh = bb - m * sc;
  key_pc[((size_t)b*256 + pos)*kC + tid] = __float2bfloat16(fmaxf(ka*sc + sh, 0.f));
  val_ck[((size_t)b*kC + tid)*256 + pos] = __float2bfloat16(va + fvalb[tid]);
}

// ---- mega tail: fc+LN -> attn -> mlp+heads -> geometry/epi (r14-proven) ----
__global__ __launch_bounds__(256) void k_tail(
    const bf16* __restrict__ catOut, const bf16* __restrict__ wfc,
    const float* __restrict__ fcb, const float* __restrict__ lng, const float* __restrict__ lnb,
    const bf16* __restrict__ key_pc, const bf16* __restrict__ val_ck,
    const float* __restrict__ fqw, const float* __restrict__ fqb,
    const float* __restrict__ aww, const float* __restrict__ awb,
    const bf16* __restrict__ mlpwT, const float* __restrict__ mlpb,
    const bf16* __restrict__ rcT, const float* __restrict__ rcb,
    const float* __restrict__ priors0, const float* __restrict__ priw_in, int stage,
    float* __restrict__ out, float* __restrict__ priw_out, float* __restrict__ pfeat_out)
{
  __shared__ __align__(16) float partS[4][16][68];  // fc partials, reused as S[16][264]
  __shared__ __align__(16) float roiL[12][68];
  __shared__ __align__(16) bf16 q[16][72];
  __shared__ __align__(16) bf16 P[16][264];
  __shared__ float rsum[16];
  __shared__ __align__(16) bf16 r2b[16][72];
  __shared__ __align__(16) bf16 h1l[16][72];
  __shared__ __align__(16) bf16 h2l[16][72];
  __shared__ float regc[12][84];
  __shared__ float ev[12][8];

  const int tid = threadIdx.x;
  const int blk = blockIdx.x, b = blk >> 4, tile = blk & 15;
  const int p0 = tile * 12;
  const int lane = tid & 63, wq = tid >> 6;
  const int lm = lane & 15, lq = lane >> 4;
  float (*S)[264] = (float (*)[264])&partS[0][0][0];

  { unsigned* z1 = (unsigned*)&q[0][0];
    for (int e = tid; e < 16*72/2; e += 256) z1[e] = 0u;
    unsigned* z2 = (unsigned*)&r2b[0][0];
    for (int e = tid; e < 16*72/2; e += 256) z2[e] = 0u; }

  {
    float4v fa[4] = {{0,0,0,0},{0,0,0,0},{0,0,0,0},{0,0,0,0}};
    int r0c = p0 + lm; if (r0c > p0 + 11) r0c = p0 + 11;
    const bf16* bb0 = catOut + (size_t)(b*kP + r0c) * 2304 + lq * 8;
    for (int kk = wq * 18; kk < wq * 18 + 18; ++kk) {
      short8v bf0 = *(const short8v*)&bb0[kk * 32];
      #pragma unroll
      for (int t = 0; t < 4; ++t) {
        short8v afrag = *(const short8v*)&wfc[((kk*4 + t)*64 + lane)*8];
        fa[t] = MFMA16(afrag, bf0, fa[t], 0, 0, 0);
      }
    }
    #pragma unroll
    for (int t = 0; t < 4; ++t)
      *(float4v*)&partS[wq][lm][t*16 + lq*4] = fa[t];
  }
  __syncthreads();
  for (int r = wq; r < 12; r += 4) {
    float v = partS[0][r][lane] + partS[1][r][lane] + partS[2][r][lane] + partS[3][r][lane]
            + fcb[lane];
    float s1 = v, s2 = v * v;
    #pragma unroll
    for (int m = 32; m; m >>= 1) { s1 += __shfl_xor(s1, m, 64); s2 += __shfl_xor(s2, m, 64); }
    float mu = s1 * (1.f/64.f);
    float var = s2 * (1.f/64.f) - mu * mu;
    float y = fmaxf((v - mu) * rsqrtf(var + 1e-5f) * lng[lane] + lnb[lane], 0.f);
    roiL[r][lane] = y;
    int p = p0 + r;
    q[r][lane] = __float2bfloat16(fmaxf(y * fqw[p] + fqb[p], 0.f));
  }
  __syncthreads();

  {
    float4v acc[4] = {{0,0,0,0},{0,0,0,0},{0,0,0,0},{0,0,0,0}};
    #pragma unroll
    for (int ks = 0; ks < 2; ++ks) {
      short8v aq0 = *(const short8v*)&q[lm][ks*32 + 8*lq];
      #pragma unroll
      for (int nt = 0; nt < 4; ++nt) {
        int pos = (wq*4 + nt)*16 + lm;
        short8v bk = *(const short8v*)&key_pc[((size_t)(b*256 + pos))*kC + ks*32 + 8*lq];
        acc[nt] = MFMA16(aq0, bk, acc[nt], 0, 0, 0);
      }
    }
    #pragma unroll
    for (int nt = 0; nt < 4; ++nt)
      #pragma unroll
      for (int r = 0; r < 4; ++r)
        S[lq*4 + r][(wq*4 + nt)*16 + lm] = acc[nt][r] * 0.125f;
  }
  __syncthreads();

  {
    int r = tid >> 4, g = tid & 15;
    float mx = -1e30f;
    #pragma unroll 16
    for (int k = 0; k < 16; ++k) { int c = g + 16*k; if (c < 250) mx = fmaxf(mx, S[r][c]); }
    #pragma unroll
    for (int m = 1; m < 16; m <<= 1) mx = fmaxf(mx, __shfl_xor(mx, m, 64));
    float sum = 0.f;
    #pragma unroll 16
    for (int k = 0; k < 16; ++k) {
      int c = g + 16*k;
      float e = 0.f;
      if (c < 250) { e = expf(S[r][c] - mx); sum += e; }
      P[r][c] = __float2bfloat16(e);
    }
    #pragma unroll
    for (int m = 1; m < 16; m <<= 1) sum += __shfl_xor(sum, m, 64);
    if (g == 0) rsum[r] = sum;
  }
  __syncthreads();

  {
    float4v acc = {0,0,0,0};
    #pragma unroll
    for (int ks = 0; ks < 8; ++ks) {
      short8v bv = *(const short8v*)&val_ck[((size_t)(b*kC + wq*16 + lm))*256 + ks*32 + 8*lq];
      short8v ap0 = *(const short8v*)&P[lm][ks*32 + 8*lq];
      acc = MFMA16(ap0, bv, acc, 0, 0, 0);
    }
    #pragma unroll
    for (int r = 0; r < 4; ++r) {
      int pl = lq*4 + r;
      if (pl < 12) {
        int p = p0 + pl, c = wq*16 + lm;
        float ctx = acc[r] / rsum[pl];
        r2b[pl][c] = __float2bfloat16(roiL[pl][c] + ctx * aww[p] + awb[p]);
      }
    }
  }
  __syncthreads();

  {
    float4v acc = {0,0,0,0};
    #pragma unroll
    for (int ks = 0; ks < 2; ++ks) {
      short8v a0 = *(const short8v*)&r2b[lm][ks*32 + 8*lq];
      short8v bw = *(const short8v*)&mlpwT[(wq*16 + lm)*kC + ks*32 + 8*lq];
      acc = MFMA16(a0, bw, acc, 0, 0, 0);
    }
    #pragma unroll
    for (int r = 0; r < 4; ++r) {
      int rw = lq*4 + r, col = wq*16 + lm;
      h1l[rw][col] = __float2bfloat16(fmaxf(acc[r] + mlpb[col], 0.f));
    }
  }
  __syncthreads();
  {
    float4v acc = {0,0,0,0};
    #pragma unroll
    for (int ks = 0; ks < 2; ++ks) {
      short8v a0 = *(const short8v*)&h1l[lm][ks*32 + 8*lq];
      short8v bw = *(const short8v*)&mlpwT[(wq*16 + lm)*kC + ks*32 + 8*lq];
      acc = MFMA16(a0, bw, acc, 0, 0, 0);
    }
    #pragma unroll
    for (int r = 0; r < 4; ++r) {
      int rw = lq*4 + r, col = wq*16 + lm;
      h2l[rw][col] = __float2bfloat16(fmaxf(acc[r] + mlpb[col], 0.f));
    }
  }
  __syncthreads();
  for (int ntile = wq; ntile < 5; ntile += 4) {
    float4v acc = {0,0,0,0};
    #pragma unroll
    for (int ks = 0; ks < 2; ++ks) {
      short8v a0 = *(const short8v*)&h2l[lm][ks*32 + 8*lq];
      short8v bw = *(const short8v*)&rcT[(ntile*16 + lm)*kC + ks*32 + 8*lq];
      acc = MFMA16(a0, bw, acc, 0, 0, 0);
    }
    #pragma unroll
    for (int r = 0; r < 4; ++r) {
      int rw = lq*4 + r, col = ntile*16 + lm;
      if (rw < 12) regc[rw][col] = acc[r] + rcb[col];
    }
  }
  __syncthreads();

  if (tid < 12) {
    int r = tid, p = p0 + r, grow = b*kP + p;
    float pr2, pr3, pr4;
    if (stage == 0) {
      pr2 = priors0[p*78 + 2]; pr3 = priors0[p*78 + 3]; pr4 = priors0[p*78 + 4];
    } else {
      const float* pw = priw_in + (size_t)grow * 78;
      pr2 = pw[2]; pr3 = pw[3]; pr4 = pw[4];
    }
    float p2 = pr2 + regc[r][0], p3 = pr3 + regc[r][1];
    float p4 = pr4 + regc[r][2], p5 = regc[r][3];
    ev[r][0] = p2; ev[r][1] = p3; ev[r][2] = p4; ev[r][3] = p5;
    ev[r][4] = 320.f / tanf(p4 * kPI + 1e-5f);
    ev[r][5] = regc[r][76]; ev[r][6] = regc[r][77];
  }
  __syncthreads();
  for (int e = tid; e < 12*78; e += 256) {
    int r = e / 78, o = e % 78;
    int p = p0 + r, grow = b*kP + p;
    float p2 = ev[r][0], p3 = ev[r][1], t320 = ev[r][4];
    float g = 0.f, v;
    if (o >= 6) g = (p3 * 799.f + ((float)(o-6) / 71.f - p2) * t320) / 799.f;
    if      (o == 0) v = ev[r][5];
    else if (o == 1) v = ev[r][6];
    else if (o == 2) v = p2;
    else if (o == 3) v = p3;
    else if (o == 4) v = ev[r][2];
    else if (o == 5) v = ev[r][3];
    else             v = g + regc[r][4 + (o - 6)];
    out[((size_t)(stage*kB + b)*kP + p) * 78 + o] = v;
    if (stage < 2) priw_out[(size_t)grow*78 + o] = (o < 6) ? v : g;
  }
  if (stage < 2) {
    for (int e = tid; e < 12*kS; e += 256) {
      int r = e / kS, si = e % kS;
      int grow = b*kP + p0 + r;
      float p2 = ev[r][0], p3 = ev[r][1], t320 = ev[r][4];
      pfeat_out[(size_t)grow*kS + si] =
          (p3 * 799.f + ((float)d_SX[si] / 71.f - p2) * t320) / 799.f;
    }
  }
}

extern "C" void kernel_launch(void* const* d_in, const int* in_sizes, int n_in,
                              void* d_out, int out_size, void* d_ws, size_t ws_size,
                              hipStream_t stream) {
  const float* x0      = (const float*)d_in[0];
  const float* x1      = (const float*)d_in[1];
  const float* x2      = (const float*)d_in[2];
  const float* priors0 = (const float*)d_in[3];
  const float* pfeat0  = (const float*)d_in[4];
  const float* conv_w  = (const float*)d_in[5];
  const float* bn_conv = (const float*)d_in[6];
  const float* cat_w[3]= {(const float*)d_in[7], (const float*)d_in[8], (const float*)d_in[9]};
  const float* bn_cat  = (const float*)d_in[10];
  const float* fkey_w  = (const float*)d_in[11];
  const float* bn_key  = (const float*)d_in[12];
  const float* fval_w  = (const float*)d_in[13];
  const float* fval_b  = (const float*)d_in[14];
  const float* fq_w    = (const float*)d_in[15];
  const float* fq_b    = (const float*)d_in[16];
  const float* attnW_w = (const float*)d_in[17];
  const float* attnW_b = (const float*)d_in[18];
  const float* fc_w    = (const float*)d_in[19];
  const float* fc_b    = (const float*)d_in[20];
  const float* ln_g    = (const float*)d_in[21];
  const float* ln_b    = (const float*)d_in[22];
  const float* mlp_w   = (const float*)d_in[23];
  const float* mlp_b   = (const float*)d_in[24];
  const float* reg_w   = (const float*)d_in[25];
  const float* reg_b   = (const float*)d_in[26];
  const float* cls_w   = (const float*)d_in[27];
  const float* cls_b   = (const float*)d_in[28];
  float* out = (float*)d_out;

  char* ws = (char*)d_ws;
  size_t off = 0;
  auto alloc = [&](size_t bytes) { void* pp = ws + off; off += (bytes + 255) & ~(size_t)255; return pp; };
  bf16* trans[3];
  for (int i = 0; i < 3; ++i) trans[i] = (bf16*)alloc((size_t)kRows * 2304 * sizeof(bf16));
  bf16*  catout = (bf16*) alloc((size_t)kRows * 2304 * sizeof(bf16));
  bf16*  key_pc[3]; bf16* val_ck[3];
  for (int i = 0; i < 3; ++i) {
    key_pc[i] = (bf16*)alloc((size_t)kB * 256 * kC * sizeof(bf16));
    val_ck[i] = (bf16*)alloc((size_t)kB * kC * 256 * sizeof(bf16));
  }
  float* priwA  = (float*)alloc((size_t)kRows * 78 * sizeof(float));
  float* priwB  = (float*)alloc((size_t)kRows * 78 * sizeof(float));
  float* pfw    = (float*)alloc((size_t)kRows * kS * sizeof(float));
  bf16* wtr[3], *wcat[3];
  const int catCI[3] = {64, 128, 192};
  for (int i = 0; i < 3; ++i) wtr[i]  = (bf16*)alloc((size_t)64*64*9 * sizeof(bf16));
  for (int i = 0; i < 3; ++i) wcat[i] = (bf16*)alloc((size_t)64*catCI[i]*9 * sizeof(bf16));
  bf16* wfc    = (bf16*)alloc((size_t)2304*64 * sizeof(bf16));
  bf16* mlpwT  = (bf16*)alloc((size_t)64*64 * sizeof(bf16));
  bf16* rcT    = (bf16*)alloc((size_t)80*64 * sizeof(bf16));
  float* rcb   = (float*)alloc((size_t)80 * sizeof(float));
  const int hd[3] = {10, 20, 40}, wd[3] = {25, 50, 100};
  bf16* fmapT[3];
  for (int i = 0; i < 3; ++i)
    fmapT[i] = (bf16*)alloc((size_t)kB * hd[i] * wd[i] * kC * sizeof(bf16));
  (void)ws_size; (void)in_sizes; (void)n_in; (void)out_size;

  // one-time preps
  for (int i = 0; i < 3; ++i) {
    int tot = 64*64*9;
    k_wprep<<<(tot+255)/256, 256, 0, stream>>>(conv_w + i*64*64*9, wtr[i], 64, tot);
  }
  for (int i = 0; i < 3; ++i) {
    int tot = 64*catCI[i]*9;
    k_wprep32<<<(tot+255)/256, 256, 0, stream>>>(cat_w[i], wcat[i], catCI[i], tot);
  }
  k_wprep_fc<<<(2304*64+255)/256, 256, 0, stream>>>(fc_w, wfc);
  k_wprep_mlpT<<<16, 256, 0, stream>>>(mlp_w, mlpwT);
  k_wprep_rct<<<20, 256, 0, stream>>>(reg_w, cls_w, reg_b, cls_b, rcT, rcb);
  const float* fmaps[3] = {x2, x1, x0};
  for (int i = 0; i < 3; ++i) {
    k_transpose<<<kB*hd[i], 256, 0, stream>>>(fmaps[i], fmapT[i], hd[i], wd[i]);
    k_keyval<<<kB*256, 64, 0, stream>>>(fmaps[i], hd[i], wd[i], fkey_w, bn_key,
                                        fval_w, fval_b, key_pc[i], val_ck[i]);
  }

  for (int st = 0; st < 3; ++st) {
    const int h = hd[st], w = wd[st];
    const float* priw_in  = (st == 1) ? priwA : priwB;   // unused at st==0
    float*       priw_out = (st == 0) ? priwA : priwB;   // ping-pong
    k_trans<<<kRows/2, 256, 0, stream>>>(fmapT[st], h, w, pfeat0, pfw, st,
                                         wtr[st], bn_conv + st*4*kC, trans[st]);
    if (st == 0)
      k_catconv32<1><<<kRows/8, 192, 0, stream>>>(trans[0], trans[1], trans[2], wcat[0],
                                                  bn_cat + st*4*kC, catout);
    else if (st == 1)
      k_catconv32<2><<<kRows/8, 192, 0, stream>>>(trans[0], trans[1], trans[2], wcat[1],
                                                  bn_cat + st*4*kC, catout);
    else
      k_catconv32<3><<<kRows/8, 192, 0, stream>>>(trans[0], trans[1], trans[2], wcat[2],
                                                  bn_cat + st*4*kC, catout);
    k_tail<<<kB*16, 256, 0, stream>>>(catout, wfc, fc_b, ln_g, ln_b,
                                      key_pc[st], val_ck[st], fq_w, fq_b, attnW_w, attnW_b,
                                      mlpwT, mlp_b, rcT, rcb,
                                      priors0, priw_in, st, out, priw_out, pfw);
  }
}

// Round 16
// 458.190 us; speedup vs baseline: 1.3576x; 1.3576x over previous
//
#include <hip/hip_runtime.h>
#include <hip/hip_bf16.h>
#include <math.h>

typedef __hip_bfloat16 bf16;
typedef __attribute__((ext_vector_type(8))) short short8v;   // 8 bf16 (4 VGPRs)
typedef __attribute__((ext_vector_type(4))) float float4v;   // MFMA accumulator

static constexpr int kB = 32;
static constexpr int kP = 192;
static constexpr int kS = 36;
static constexpr int kC = 64;
static constexpr int kRows = kB * kP;   // 6144
static constexpr float kPI = 3.14159265358979323846f;

__device__ __constant__ int d_SX[36] = {
  0,2,4,6,8,10,12,14,16,18,20,22,24,26,28,30,32,34,
  36,38,40,42,44,46,48,50,52,54,56,58,60,62,64,66,68,71};

__device__ __forceinline__ float b2f(bf16 v) { return __bfloat162float(v); }
__device__ __forceinline__ unsigned short f2bu(float f) {
  bf16 h = __float2bfloat16(f);
  return *reinterpret_cast<unsigned short*>(&h);
}
__device__ __forceinline__ float su2f(unsigned short u) {
  bf16 t; *reinterpret_cast<unsigned short*>(&t) = u; return __bfloat162float(t);
}
#define MFMA16 __builtin_amdgcn_mfma_f32_16x16x32_bf16

// ---- conv weight prep helper: (CO=64, CI, 9) f32 -> fragment-linear bf16 ----
// dst layout: [t][chi][wid][lane][8]; co = wid*16+(l&15); ci = chi*32+8*(l>>4)+j
__device__ __forceinline__ void wprep_one(
    int d, const float* __restrict__ src, bf16* __restrict__ dst, int CI)
{
  int j   = d & 7;
  int l   = (d >> 3) & 63;
  int wid = (d >> 9) & 3;
  int r   = d >> 11;
  int nchi = CI >> 5;
  int chi = r % nchi, t = r / nchi;
  int co = wid * 16 + (l & 15);
  int ci = chi * 32 + 8 * (l >> 4) + j;
  dst[d] = __float2bfloat16(src[(co * CI + ci) * 9 + t]);
}

// ---- merged prep: all conv wfrags + fc + mlpT + rcT/rcb in ONE dispatch ----
// segment boundaries (elements):
//  wtr0 36864 | wtr1 36864 | wtr2 36864 | wcat0 36864 | wcat1 73728 | wcat2 110592
//  wfc 147456 | mlpT 4096 | rc 5120   => total 488448
__global__ __launch_bounds__(256) void k_prep_all(
    const float* __restrict__ conv_w,
    const float* __restrict__ cat_w0, const float* __restrict__ cat_w1,
    const float* __restrict__ cat_w2,
    const float* __restrict__ fc_w, const float* __restrict__ mlp_w,
    const float* __restrict__ regw, const float* __restrict__ regb,
    const float* __restrict__ clsw, const float* __restrict__ clsb,
    bf16* __restrict__ wtr0, bf16* __restrict__ wtr1, bf16* __restrict__ wtr2,
    bf16* __restrict__ wcat0, bf16* __restrict__ wcat1, bf16* __restrict__ wcat2,
    bf16* __restrict__ wfc, bf16* __restrict__ mlpwT,
    bf16* __restrict__ rcT, float* __restrict__ rcb)
{
  int d = blockIdx.x * 256 + threadIdx.x;
  if (d < 36864)        { wprep_one(d, conv_w,               wtr0, 64); return; }
  d -= 36864;
  if (d < 36864)        { wprep_one(d, conv_w + 36864,       wtr1, 64); return; }
  d -= 36864;
  if (d < 36864)        { wprep_one(d, conv_w + 2*36864,     wtr2, 64); return; }
  d -= 36864;
  if (d < 36864)        { wprep_one(d, cat_w0, wcat0, 64);  return; }
  d -= 36864;
  if (d < 73728)        { wprep_one(d, cat_w1, wcat1, 128); return; }
  d -= 73728;
  if (d < 110592)       { wprep_one(d, cat_w2, wcat2, 192); return; }
  d -= 110592;
  if (d < 147456) {     // fc: [72][4][64][8]; k = s*64 + c ; src (c*36+s, 64)
    int j    = d & 7;
    int l    = (d >> 3) & 63;
    int tile = (d >> 9) & 3;
    int kk   = d >> 11;
    int cout = tile * 16 + (l & 15);
    int k    = kk * 32 + 8 * (l >> 4) + j;
    int c = k & 63, s = k >> 6;
    wfc[d] = __float2bfloat16(fc_w[(c * kS + s) * kC + cout]);
    return;
  }
  d -= 147456;
  if (d < 4096) {       // mlpwT [cout][cin]
    int co = d >> 6, ci = d & 63;
    mlpwT[d] = __float2bfloat16(mlp_w[ci * 64 + co]);
    return;
  }
  d -= 4096;
  if (d < 5120) {       // rcT [80][64]
    int o = d >> 6, ci = d & 63;
    float v = (o < 76) ? regw[ci * 76 + o] : (o < 78 ? clsw[ci * 2 + (o - 76)] : 0.f);
    rcT[d] = __float2bfloat16(v);
    if (d < 80) rcb[d] = (d < 76) ? regb[d] : (d < 78 ? clsb[d - 76] : 0.f);
  }
}

// ---- merged fmap transpose for ALL 3 stages: [b][c][h][w] f32 -> [b][y][x][c] bf16 ----
// grid = kB*(10+20+40) = 2240; stage decoded from block index
__global__ __launch_bounds__(256) void k_transpose3(
    const float* __restrict__ x2, const float* __restrict__ x1, const float* __restrict__ x0,
    bf16* __restrict__ f0, bf16* __restrict__ f1, bf16* __restrict__ f2)
{
  __shared__ float tile[64][65];
  int byA = blockIdx.x;
  const float* src; bf16* dst; int h, w;
  if (byA < kB*10)            { src = x2; dst = f0; h = 10; w = 25;  }
  else if (byA < kB*30)       { src = x1; dst = f1; h = 20; w = 50;  byA -= kB*10; }
  else                        { src = x0; dst = f2; h = 40; w = 100; byA -= kB*30; }
  const int b = byA / h, y = byA % h;
  const int lane = threadIdx.x & 63, wq = threadIdx.x >> 6;
  for (int x0i = 0; x0i < w; x0i += 64) {
    #pragma unroll
    for (int cc = 0; cc < 16; ++cc) {
      int c = wq * 16 + cc;
      int x = x0i + lane;
      if (x < w) tile[c][lane] = src[((size_t)(b*kC + c)*h + y)*w + x];
    }
    __syncthreads();
    #pragma unroll
    for (int xx = 0; xx < 16; ++xx) {
      int x = x0i + wq * 16 + xx;
      if (x < w) dst[((size_t)(b*h + y)*w + x)*kC + lane] = __float2bfloat16(tile[lane][wq*16 + xx]);
    }
    __syncthreads();
  }
}

// ---- merged key/value for ALL 3 stages ----
// grid = 3*kB*256; key -> [b][pos256][c], val -> [b][c][pos256]
__global__ __launch_bounds__(64) void k_keyval3(
    const float* __restrict__ x2, const float* __restrict__ x1, const float* __restrict__ x0,
    const float* __restrict__ fkeyw, const float* __restrict__ bnk,
    const float* __restrict__ fvalw, const float* __restrict__ fvalb,
    bf16* __restrict__ k0, bf16* __restrict__ v0,
    bf16* __restrict__ k1, bf16* __restrict__ v1,
    bf16* __restrict__ k2, bf16* __restrict__ v2)
{
  const int tid = threadIdx.x;
  int blk = blockIdx.x;
  const int stage = blk / (kB*256);
  blk -= stage * (kB*256);
  const float* fmap; bf16 *key_pc, *val_ck; int h, w;
  if (stage == 0)      { fmap = x2; key_pc = k0; val_ck = v0; h = 10; w = 25;  }
  else if (stage == 1) { fmap = x1; key_pc = k1; val_ck = v1; h = 20; w = 50;  }
  else                 { fmap = x0; key_pc = k2; val_ck = v2; h = 40; w = 100; }
  const int b = blk >> 8, pos = blk & 255;
  if (pos >= 250) {
    key_pc[((size_t)b*256 + pos)*kC + tid] = __float2bfloat16(0.f);
    val_ck[((size_t)b*kC + tid)*256 + pos] = __float2bfloat16(0.f);
    return;
  }
  const int i = pos / 25, j = pos % 25;
  const int yi = (i * h) / 10, xj = (j * w) / 25;
  __shared__ float fv[kC];
  fv[tid] = fmap[((size_t)(b*kC + tid) * h + yi) * w + xj];
  __syncthreads();
  float ka = 0.f, va = 0.f;
  const float* kr = fkeyw + tid * kC;
  const float* vr = fvalw + tid * kC;
  for (int c = 0; c < kC; ++c) { float f = fv[c]; ka += f * kr[c]; va += f * vr[c]; }
  float g = bnk[tid], bb = bnk[kC + tid];
  float m = bnk[2*kC + tid], v = bnk[3*kC + tid];
  float sc = g / sqrtf(v + 1e-5f), sh = bb - m * sc;
  key_pc[((size_t)b*256 + pos)*kC + tid] = __float2bfloat16(fmaxf(ka*sc + sh, 0.f));
  val_ck[((size_t)b*kC + tid)*256 + pos] = __float2bfloat16(va + fvalb[tid]);
}

// ---- fused grid_sample + conv1d(k9,pad4) MFMA + BN + ReLU ; 2 rows/block ----
// wave = (row r2, cout-pair cp): 1 ds_read feeds 2 MFMA (ds:MFMA = 1:2)
__global__ __launch_bounds__(256) void k_trans(
    const bf16* __restrict__ fmapT, int h, int w,
    const float* __restrict__ pfeat0, const float* __restrict__ pfeatw, int stage,
    const bf16* __restrict__ wfrag,     // fragment-linear [9][2][4][64][8]
    const float* __restrict__ bnp,      // (4,64) f32
    bf16* __restrict__ transOut)        // (6144,36,64) bf16
{
  __shared__ __align__(16) bf16 poolT[2][56][64];
  __shared__ float bsc[kC], bsh[kC];
  const int tid = threadIdx.x;
  const int row0 = blockIdx.x * 2, b = row0 / kP;

  if (tid < kC) {
    float g = bnp[tid], bb = bnp[kC + tid];
    float m = bnp[2*kC + tid], v = bnp[3*kC + tid];
    float sc = g / sqrtf(v + 1e-5f);
    bsc[tid] = sc; bsh[tid] = bb - m * sc;
  }
  unsigned int* pz = (unsigned int*)&poolT[0][0][0];
  for (int e = tid; e < 2*56*32; e += 256) pz[e] = 0u;
  __syncthreads();

  // sampling: 8-lane group per (row,sample); lane covers 8 channels (one slot)
  const int lc = tid & 7;
  for (int idx = tid >> 3; idx < 2*kS; idx += 32) {
    int r2 = idx / kS, s = idx % kS;
    int row = row0 + r2, p = row % kP;
    float px = (stage == 0) ? pfeat0[p*kS + (kS-1-s)] : pfeatw[row*kS + (kS-1-s)];
    float fy = 1.0f - (float)d_SX[kS-1-s] / 71.0f;
    float x = px * (float)(w - 1);
    float y = fy * (float)(h - 1);
    float x0f = floorf(x), y0f = floorf(y);
    float wx = x - x0f, wy = y - y0f;
    int xi = (int)x0f, yi = (int)y0f;
    float a8[8];
    #pragma unroll
    for (int j = 0; j < 8; ++j) a8[j] = 0.f;
    #pragma unroll
    for (int cy = 0; cy < 2; ++cy) {
      #pragma unroll
      for (int cx = 0; cx < 2; ++cx) {
        int xx = xi + cx, yy = yi + cy;
        if (xx >= 0 && xx < w && yy >= 0 && yy < h) {
          float wgt = (cx ? wx : 1.f - wx) * (cy ? wy : 1.f - wy);
          short8v v = *(const short8v*)&fmapT[((size_t)(b*h + yy)*w + xx)*kC + lc*8];
          #pragma unroll
          for (int j = 0; j < 8; ++j)
            a8[j] += su2f((unsigned short)v[j]) * wgt;
        }
      }
    }
    uint4 pk;
    pk.x = (unsigned)f2bu(a8[0]) | ((unsigned)f2bu(a8[1]) << 16);
    pk.y = (unsigned)f2bu(a8[2]) | ((unsigned)f2bu(a8[3]) << 16);
    pk.z = (unsigned)f2bu(a8[4]) | ((unsigned)f2bu(a8[5]) << 16);
    pk.w = (unsigned)f2bu(a8[6]) | ((unsigned)f2bu(a8[7]) << 16);
    int lr = s + 4;
    *reinterpret_cast<uint4*>(&poolT[r2][lr][((lc + lr) & 7)*8]) = pk;
  }
  __syncthreads();

  const int wv = tid >> 6, lane = tid & 63;
  const int r2 = wv & 1, cp = wv >> 1;    // wave = (row, cout-pair)
  const int lm = lane & 15, lq = lane >> 4;
  float4v acc[2][3] = {{{0,0,0,0},{0,0,0,0},{0,0,0,0}},{{0,0,0,0},{0,0,0,0},{0,0,0,0}}};
  #pragma unroll
  for (int t = 0; t < 9; ++t) {
    #pragma unroll
    for (int chi = 0; chi < 2; ++chi) {
      short8v a0 = *(const short8v*)&wfrag[(((t*2 + chi)*4 + cp*2 + 0)*64 + lane)*8];
      short8v a1 = *(const short8v*)&wfrag[(((t*2 + chi)*4 + cp*2 + 1)*64 + lane)*8];
      #pragma unroll
      for (int nt = 0; nt < 3; ++nt) {
        int rr = nt*16 + lm + t;
        int sl = chi*4 + lq;
        short8v bb = *(const short8v*)&poolT[r2][rr][((sl + rr) & 7)*8];
        acc[0][nt] = MFMA16(a0, bb, acc[0][nt], 0, 0, 0);
        acc[1][nt] = MFMA16(a1, bb, acc[1][nt], 0, 0, 0);
      }
    }
  }
  #pragma unroll
  for (int c2 = 0; c2 < 2; ++c2) {
    const int c4 = (cp*2 + c2)*16 + 4*lq;
    float s0 = bsc[c4], s1 = bsc[c4+1], s2 = bsc[c4+2], s3 = bsc[c4+3];
    float h0 = bsh[c4], h1 = bsh[c4+1], h2 = bsh[c4+2], h3 = bsh[c4+3];
    #pragma unroll
    for (int nt = 0; nt < 3; ++nt) {
      int s = nt*16 + lm;
      if (s < kS) {
        uint2 pk;
        pk.x = (unsigned)f2bu(fmaxf(acc[c2][nt][0]*s0 + h0, 0.f))
             | ((unsigned)f2bu(fmaxf(acc[c2][nt][1]*s1 + h1, 0.f)) << 16);
        pk.y = (unsigned)f2bu(fmaxf(acc[c2][nt][2]*s2 + h2, 0.f))
             | ((unsigned)f2bu(fmaxf(acc[c2][nt][3]*s3 + h3, 0.f)) << 16);
        *reinterpret_cast<uint2*>(&transOut[((size_t)(row0+r2)*kS + s)*kC + c4]) = pk;
      }
    }
  }
}

// ---- concat(trans[0..st]) -> conv1d(k9,pad4) via MFMA + BN + ReLU ; 2 rows/block ----
// wave = (row r2, cout-pair cp): 1 ds_read feeds 2 MFMA (ds:MFMA = 1:2); 0-conflict swizzle
template<int NCI>
__global__ __launch_bounds__(256) void k_catconv(
    const bf16* __restrict__ t0, const bf16* __restrict__ t1, const bf16* __restrict__ t2,
    const bf16* __restrict__ wfrag,   // [9][NCI/32][4][64][8]
    const float* __restrict__ bnp, bf16* __restrict__ catOut)
{
  constexpr int CB = NCI/8;           // slots per row
  __shared__ __align__(16) bf16 poolT[2][56][NCI];
  __shared__ float bsc[kC], bsh[kC];
  const int tid = threadIdx.x;
  const int row0 = blockIdx.x * 2;
  if (tid < kC) {
    float g = bnp[tid], bb = bnp[kC + tid];
    float m = bnp[2*kC + tid], v = bnp[3*kC + tid];
    float sc = g / sqrtf(v + 1e-5f);
    bsc[tid] = sc; bsh[tid] = bb - m * sc;
  }
  unsigned int* pz = (unsigned int*)&poolT[0][0][0];
  for (int e = tid; e < 2*56*NCI/2; e += 256) pz[e] = 0u;
  __syncthreads();

  const bf16* tb[3] = {t0, t1, t2};
  for (int cc = tid; cc < 2*kS*CB; cc += 256) {
    int r2 = cc / (kS*CB), rem = cc % (kS*CB);
    int s = rem / CB, cb = rem % CB;
    int ch = cb * 8, i = ch >> 6, c = ch & 63;
    const short8v* src = (const short8v*)&tb[i][((size_t)(row0+r2)*kS + s)*kC + c];
    int lr = s + 4;
    int sl = (cb & ~7) | ((cb + lr) & 7);
    *(short8v*)&poolT[r2][lr][sl*8] = *src;
  }
  __syncthreads();

  const int wv = tid >> 6, lane = tid & 63;
  const int r2 = wv & 1, cp = wv >> 1;    // wave = (row, cout-pair)
  const int lm = lane & 15, lq = lane >> 4;
  float4v acc[2][3] = {{{0,0,0,0},{0,0,0,0},{0,0,0,0}},{{0,0,0,0},{0,0,0,0},{0,0,0,0}}};
  #pragma unroll
  for (int t = 0; t < 9; ++t) {
    #pragma unroll
    for (int chi = 0; chi < NCI/32; ++chi) {
      short8v a0 = *(const short8v*)&wfrag[(((t*(NCI/32) + chi)*4 + cp*2 + 0)*64 + lane)*8];
      short8v a1 = *(const short8v*)&wfrag[(((t*(NCI/32) + chi)*4 + cp*2 + 1)*64 + lane)*8];
      #pragma unroll
      for (int nt = 0; nt < 3; ++nt) {
        int rr = nt*16 + lm + t;
        int sl0 = chi*4 + lq;
        int sl = (sl0 & ~7) | ((sl0 + rr) & 7);
        short8v bb = *(const short8v*)&poolT[r2][rr][sl*8];
        acc[0][nt] = MFMA16(a0, bb, acc[0][nt], 0, 0, 0);
        acc[1][nt] = MFMA16(a1, bb, acc[1][nt], 0, 0, 0);
      }
    }
  }
  #pragma unroll
  for (int c2 = 0; c2 < 2; ++c2) {
    const int c4 = (cp*2 + c2)*16 + 4*lq;
    float s0 = bsc[c4], s1 = bsc[c4+1], s2 = bsc[c4+2], s3 = bsc[c4+3];
    float h0 = bsh[c4], h1 = bsh[c4+1], h2 = bsh[c4+2], h3 = bsh[c4+3];
    #pragma unroll
    for (int nt = 0; nt < 3; ++nt) {
      int s = nt*16 + lm;
      if (s < kS) {
        uint2 pk;
        pk.x = (unsigned)f2bu(fmaxf(acc[c2][nt][0]*s0 + h0, 0.f))
             | ((unsigned)f2bu(fmaxf(acc[c2][nt][1]*s1 + h1, 0.f)) << 16);
        pk.y = (unsigned)f2bu(fmaxf(acc[c2][nt][2]*s2 + h2, 0.f))
             | ((unsigned)f2bu(fmaxf(acc[c2][nt][3]*s3 + h3, 0.f)) << 16);
        *reinterpret_cast<uint2*>(&catOut[((size_t)(row0+r2)*kS + s)*kC + c4]) = pk;
      }
    }
  }
}

// ---- mega tail: fc+LN -> attn(QK^T, softmax, PV, residual) -> mlp+heads -> geometry/epi ----
// block = (b, tile of 12 rows); grid = 32*16 = 512 ; ~43KB LDS -> 3 blocks/CU
__global__ __launch_bounds__(256) void k_tail(
    const bf16* __restrict__ catOut, const bf16* __restrict__ wfc,
    const float* __restrict__ fcb, const float* __restrict__ lng, const float* __restrict__ lnb,
    const bf16* __restrict__ key_pc, const bf16* __restrict__ val_ck,
    const float* __restrict__ fqw, const float* __restrict__ fqb,
    const float* __restrict__ aww, const float* __restrict__ awb,
    const bf16* __restrict__ mlpwT, const float* __restrict__ mlpb,
    const bf16* __restrict__ rcT, const float* __restrict__ rcb,
    const float* __restrict__ priors0, const float* __restrict__ priw_in, int stage,
    float* __restrict__ out, float* __restrict__ priw_out, float* __restrict__ pfeat_out)
{
  __shared__ __align__(16) float partS[4][16][68];  // fc partials, reused as S[16][264]
  __shared__ __align__(16) float roiL[12][68];
  __shared__ __align__(16) bf16 q[16][72];
  __shared__ __align__(16) bf16 P[16][264];
  __shared__ float rsum[16];
  __shared__ __align__(16) bf16 r2b[16][72];
  __shared__ __align__(16) bf16 h1l[16][72];
  __shared__ __align__(16) bf16 h2l[16][72];
  __shared__ float regc[12][84];
  __shared__ float ev[12][8];

  const int tid = threadIdx.x;
  const int blk = blockIdx.x, b = blk >> 4, tile = blk & 15;
  const int p0 = tile * 12;
  const int lane = tid & 63, wq = tid >> 6;
  const int lm = lane & 15, lq = lane >> 4;
  float (*S)[264] = (float (*)[264])&partS[0][0][0];

  { unsigned* z1 = (unsigned*)&q[0][0];
    for (int e = tid; e < 16*72/2; e += 256) z1[e] = 0u;
    unsigned* z2 = (unsigned*)&r2b[0][0];
    for (int e = tid; e < 16*72/2; e += 256) z2[e] = 0u; }

  {
    float4v fa[4] = {{0,0,0,0},{0,0,0,0},{0,0,0,0},{0,0,0,0}};
    int r0c = p0 + lm; if (r0c > p0 + 11) r0c = p0 + 11;
    const bf16* bb0 = catOut + (size_t)(b*kP + r0c) * 2304 + lq * 8;
    for (int kk = wq * 18; kk < wq * 18 + 18; ++kk) {
      short8v bf0 = *(const short8v*)&bb0[kk * 32];
      #pragma unroll
      for (int t = 0; t < 4; ++t) {
        short8v afrag = *(const short8v*)&wfc[((kk*4 + t)*64 + lane)*8];
        fa[t] = MFMA16(afrag, bf0, fa[t], 0, 0, 0);
      }
    }
    #pragma unroll
    for (int t = 0; t < 4; ++t)
      *(float4v*)&partS[wq][lm][t*16 + lq*4] = fa[t];
  }
  __syncthreads();
  for (int r = wq; r < 12; r += 4) {
    float v = partS[0][r][lane] + partS[1][r][lane] + partS[2][r][lane] + partS[3][r][lane]
            + fcb[lane];
    float s1 = v, s2 = v * v;
    #pragma unroll
    for (int m = 32; m; m >>= 1) { s1 += __shfl_xor(s1, m, 64); s2 += __shfl_xor(s2, m, 64); }
    float mu = s1 * (1.f/64.f);
    float var = s2 * (1.f/64.f) - mu * mu;
    float y = fmaxf((v - mu) * rsqrtf(var + 1e-5f) * lng[lane] + lnb[lane], 0.f);
    roiL[r][lane] = y;
    int p = p0 + r;
    q[r][lane] = __float2bfloat16(fmaxf(y * fqw[p] + fqb[p], 0.f));
  }
  __syncthreads();

  {
    float4v acc[4] = {{0,0,0,0},{0,0,0,0},{0,0,0,0},{0,0,0,0}};
    #pragma unroll
    for (int ks = 0; ks < 2; ++ks) {
      short8v aq0 = *(const short8v*)&q[lm][ks*32 + 8*lq];
      #pragma unroll
      for (int nt = 0; nt < 4; ++nt) {
        int pos = (wq*4 + nt)*16 + lm;
        short8v bk = *(const short8v*)&key_pc[((size_t)(b*256 + pos))*kC + ks*32 + 8*lq];
        acc[nt] = MFMA16(aq0, bk, acc[nt], 0, 0, 0);
      }
    }
    #pragma unroll
    for (int nt = 0; nt < 4; ++nt)
      #pragma unroll
      for (int r = 0; r < 4; ++r)
        S[lq*4 + r][(wq*4 + nt)*16 + lm] = acc[nt][r] * 0.125f;
  }
  __syncthreads();

  {
    int r = tid >> 4, g = tid & 15;
    float mx = -1e30f;
    #pragma unroll 16
    for (int k = 0; k < 16; ++k) { int c = g + 16*k; if (c < 250) mx = fmaxf(mx, S[r][c]); }
    #pragma unroll
    for (int m = 1; m < 16; m <<= 1) mx = fmaxf(mx, __shfl_xor(mx, m, 64));
    float sum = 0.f;
    #pragma unroll 16
    for (int k = 0; k < 16; ++k) {
      int c = g + 16*k;
      float e = 0.f;
      if (c < 250) { e = expf(S[r][c] - mx); sum += e; }
      P[r][c] = __float2bfloat16(e);
    }
    #pragma unroll
    for (int m = 1; m < 16; m <<= 1) sum += __shfl_xor(sum, m, 64);
    if (g == 0) rsum[r] = sum;
  }
  __syncthreads();

  {
    float4v acc = {0,0,0,0};
    #pragma unroll
    for (int ks = 0; ks < 8; ++ks) {
      short8v bv = *(const short8v*)&val_ck[((size_t)(b*kC + wq*16 + lm))*256 + ks*32 + 8*lq];
      short8v ap0 = *(const short8v*)&P[lm][ks*32 + 8*lq];
      acc = MFMA16(ap0, bv, acc, 0, 0, 0);
    }
    #pragma unroll
    for (int r = 0; r < 4; ++r) {
      int pl = lq*4 + r;
      if (pl < 12) {
        int p = p0 + pl, c = wq*16 + lm;
        float ctx = acc[r] / rsum[pl];
        r2b[pl][c] = __float2bfloat16(roiL[pl][c] + ctx * aww[p] + awb[p]);
      }
    }
  }
  __syncthreads();

  {
    float4v acc = {0,0,0,0};
    #pragma unroll
    for (int ks = 0; ks < 2; ++ks) {
      short8v a0 = *(const short8v*)&r2b[lm][ks*32 + 8*lq];
      short8v bw = *(const short8v*)&mlpwT[(wq*16 + lm)*kC + ks*32 + 8*lq];
      acc = MFMA16(a0, bw, acc, 0, 0, 0);
    }
    #pragma unroll
    for (int r = 0; r < 4; ++r) {
      int rw = lq*4 + r, col = wq*16 + lm;
      h1l[rw][col] = __float2bfloat16(fmaxf(acc[r] + mlpb[col], 0.f));
    }
  }
  __syncthreads();
  {
    float4v acc = {0,0,0,0};
    #pragma unroll
    for (int ks = 0; ks < 2; ++ks) {
      short8v a0 = *(const short8v*)&h1l[lm][ks*32 + 8*lq];
      short8v bw = *(const short8v*)&mlpwT[(wq*16 + lm)*kC + ks*32 + 8*lq];
      acc = MFMA16(a0, bw, acc, 0, 0, 0);
    }
    #pragma unroll
    for (int r = 0; r < 4; ++r) {
      int rw = lq*4 + r, col = wq*16 + lm;
      h2l[rw][col] = __float2bfloat16(fmaxf(acc[r] + mlpb[col], 0.f));
    }
  }
  __syncthreads();
  for (int ntile = wq; ntile < 5; ntile += 4) {
    float4v acc = {0,0,0,0};
    #pragma unroll
    for (int ks = 0; ks < 2; ++ks) {
      short8v a0 = *(const short8v*)&h2l[lm][ks*32 + 8*lq];
      short8v bw = *(const short8v*)&rcT[(ntile*16 + lm)*kC + ks*32 + 8*lq];
      acc = MFMA16(a0, bw, acc, 0, 0, 0);
    }
    #pragma unroll
    for (int r = 0; r < 4; ++r) {
      int rw = lq*4 + r, col = ntile*16 + lm;
      if (rw < 12) regc[rw][col] = acc[r] + rcb[col];
    }
  }
  __syncthreads();

  if (tid < 12) {
    int r = tid, p = p0 + r, grow = b*kP + p;
    float pr2, pr3, pr4;
    if (stage == 0) {
      pr2 = priors0[p*78 + 2]; pr3 = priors0[p*78 + 3]; pr4 = priors0[p*78 + 4];
    } else {
      const float* pw = priw_in + (size_t)grow * 78;
      pr2 = pw[2]; pr3 = pw[3]; pr4 = pw[4];
    }
    float p2 = pr2 + regc[r][0], p3 = pr3 + regc[r][1];
    float p4 = pr4 + regc[r][2], p5 = regc[r][3];
    ev[r][0] = p2; ev[r][1] = p3; ev[r][2] = p4; ev[r][3] = p5;
    ev[r][4] = 320.f / tanf(p4 * kPI + 1e-5f);
    ev[r][5] = regc[r][76]; ev[r][6] = regc[r][77];
  }
  __syncthreads();
  for (int e = tid; e < 12*78; e += 256) {
    int r = e / 78, o = e % 78;
    int p = p0 + r, grow = b*kP + p;
    float p2 = ev[r][0], p3 = ev[r][1], t320 = ev[r][4];
    float g = 0.f, v;
    if (o >= 6) g = (p3 * 799.f + ((float)(o-6) / 71.f - p2) * t320) / 799.f;
    if      (o == 0) v = ev[r][5];
    else if (o == 1) v = ev[r][6];
    else if (o == 2) v = p2;
    else if (o == 3) v = p3;
    else if (o == 4) v = ev[r][2];
    else if (o == 5) v = ev[r][3];
    else             v = g + regc[r][4 + (o - 6)];
    out[((size_t)(stage*kB + b)*kP + p) * 78 + o] = v;
    if (stage < 2) priw_out[(size_t)grow*78 + o] = (o < 6) ? v : g;
  }
  if (stage < 2) {
    for (int e = tid; e < 12*kS; e += 256) {
      int r = e / kS, si = e % kS;
      int grow = b*kP + p0 + r;
      float p2 = ev[r][0], p3 = ev[r][1], t320 = ev[r][4];
      pfeat_out[(size_t)grow*kS + si] =
          (p3 * 799.f + ((float)d_SX[si] / 71.f - p2) * t320) / 799.f;
    }
  }
}

extern "C" void kernel_launch(void* const* d_in, const int* in_sizes, int n_in,
                              void* d_out, int out_size, void* d_ws, size_t ws_size,
                              hipStream_t stream) {
  const float* x0      = (const float*)d_in[0];
  const float* x1      = (const float*)d_in[1];
  const float* x2      = (const float*)d_in[2];
  const float* priors0 = (const float*)d_in[3];
  const float* pfeat0  = (const float*)d_in[4];
  const float* conv_w  = (const float*)d_in[5];
  const float* bn_conv = (const float*)d_in[6];
  const float* cat_w[3]= {(const float*)d_in[7], (const float*)d_in[8], (const float*)d_in[9]};
  const float* bn_cat  = (const float*)d_in[10];
  const float* fkey_w  = (const float*)d_in[11];
  const float* bn_key  = (const float*)d_in[12];
  const float* fval_w  = (const float*)d_in[13];
  const float* fval_b  = (const float*)d_in[14];
  const float* fq_w    = (const float*)d_in[15];
  const float* fq_b    = (const float*)d_in[16];
  const float* attnW_w = (const float*)d_in[17];
  const float* attnW_b = (const float*)d_in[18];
  const float* fc_w    = (const float*)d_in[19];
  const float* fc_b    = (const float*)d_in[20];
  const float* ln_g    = (const float*)d_in[21];
  const float* ln_b    = (const float*)d_in[22];
  const float* mlp_w   = (const float*)d_in[23];
  const float* mlp_b   = (const float*)d_in[24];
  const float* reg_w   = (const float*)d_in[25];
  const float* reg_b   = (const float*)d_in[26];
  const float* cls_w   = (const float*)d_in[27];
  const float* cls_b   = (const float*)d_in[28];
  float* out = (float*)d_out;

  char* ws = (char*)d_ws;
  size_t off = 0;
  auto alloc = [&](size_t bytes) { void* pp = ws + off; off += (bytes + 255) & ~(size_t)255; return pp; };
  bf16* trans[3];
  for (int i = 0; i < 3; ++i) trans[i] = (bf16*)alloc((size_t)kRows * 2304 * sizeof(bf16));
  bf16*  catout = (bf16*) alloc((size_t)kRows * 2304 * sizeof(bf16));
  bf16*  key_pc[3]; bf16* val_ck[3];
  for (int i = 0; i < 3; ++i) {
    key_pc[i] = (bf16*)alloc((size_t)kB * 256 * kC * sizeof(bf16));
    val_ck[i] = (bf16*)alloc((size_t)kB * kC * 256 * sizeof(bf16));
  }
  float* priwA  = (float*)alloc((size_t)kRows * 78 * sizeof(float));
  float* priwB  = (float*)alloc((size_t)kRows * 78 * sizeof(float));
  float* pfw    = (float*)alloc((size_t)kRows * kS * sizeof(float));
  bf16* wtr[3], *wcat[3];
  const int catCI[3] = {64, 128, 192};
  for (int i = 0; i < 3; ++i) wtr[i]  = (bf16*)alloc((size_t)64*64*9 * sizeof(bf16));
  for (int i = 0; i < 3; ++i) wcat[i] = (bf16*)alloc((size_t)64*catCI[i]*9 * sizeof(bf16));
  bf16* wfc    = (bf16*)alloc((size_t)2304*64 * sizeof(bf16));
  bf16* mlpwT  = (bf16*)alloc((size_t)64*64 * sizeof(bf16));
  bf16* rcT    = (bf16*)alloc((size_t)80*64 * sizeof(bf16));
  float* rcb   = (float*)alloc((size_t)80 * sizeof(float));
  const int hd[3] = {10, 20, 40}, wd[3] = {25, 50, 100};
  bf16* fmapT[3];
  for (int i = 0; i < 3; ++i)
    fmapT[i] = (bf16*)alloc((size_t)kB * hd[i] * wd[i] * kC * sizeof(bf16));
  (void)ws_size; (void)in_sizes; (void)n_in; (void)out_size;

  // merged one-time preps: 3 dispatches instead of 15
  k_prep_all<<<(488448 + 255)/256, 256, 0, stream>>>(
      conv_w, cat_w[0], cat_w[1], cat_w[2], fc_w, mlp_w, reg_w, reg_b, cls_w, cls_b,
      wtr[0], wtr[1], wtr[2], wcat[0], wcat[1], wcat[2], wfc, mlpwT, rcT, rcb);
  k_transpose3<<<kB*70, 256, 0, stream>>>(x2, x1, x0, fmapT[0], fmapT[1], fmapT[2]);
  k_keyval3<<<3*kB*256, 64, 0, stream>>>(x2, x1, x0, fkey_w, bn_key, fval_w, fval_b,
                                         key_pc[0], val_ck[0], key_pc[1], val_ck[1],
                                         key_pc[2], val_ck[2]);

  for (int st = 0; st < 3; ++st) {
    const int h = hd[st], w = wd[st];
    const float* priw_in  = (st == 1) ? priwA : priwB;   // unused at st==0
    float*       priw_out = (st == 0) ? priwA : priwB;   // ping-pong
    k_trans<<<kRows/2, 256, 0, stream>>>(fmapT[st], h, w, pfeat0, pfw, st,
                                         wtr[st], bn_conv + st*4*kC, trans[st]);
    if (st == 0)
      k_catconv<64><<<kRows/2, 256, 0, stream>>>(trans[0], trans[1], trans[2], wcat[0],
                                                 bn_cat + st*4*kC, catout);
    else if (st == 1)
      k_catconv<128><<<kRows/2, 256, 0, stream>>>(trans[0], trans[1], trans[2], wcat[1],
                                                  bn_cat + st*4*kC, catout);
    else
      k_catconv<192><<<kRows/2, 256, 0, stream>>>(trans[0], trans[1], trans[2], wcat[2],
                                                  bn_cat + st*4*kC, catout);
    k_tail<<<kB*16, 256, 0, stream>>>(catout, wfc, fc_b, ln_g, ln_b,
                                      key_pc[st], val_ck[st], fq_w, fq_b, attnW_w, attnW_b,
                                      mlpwT, mlp_b, rcT, rcb,
                                      priors0, priw_in, st, out, priw_out, pfw);
  }
}

// Round 17
// 451.728 us; speedup vs baseline: 1.3770x; 1.0143x over previous
//
#include <hip/hip_runtime.h>
#include <hip/hip_bf16.h>
#include <math.h>

typedef __hip_bfloat16 bf16;
typedef __attribute__((ext_vector_type(8))) short short8v;   // 8 bf16 (4 VGPRs)
typedef __attribute__((ext_vector_type(4))) float float4v;   // MFMA accumulator

static constexpr int kB = 32;
static constexpr int kP = 192;
static constexpr int kS = 36;
static constexpr int kC = 64;
static constexpr int kRows = kB * kP;   // 6144
static constexpr float kPI = 3.14159265358979323846f;

__device__ __constant__ int d_SX[36] = {
  0,2,4,6,8,10,12,14,16,18,20,22,24,26,28,30,32,34,
  36,38,40,42,44,46,48,50,52,54,56,58,60,62,64,66,68,71};

__device__ __forceinline__ float b2f(bf16 v) { return __bfloat162float(v); }
__device__ __forceinline__ unsigned short f2bu(float f) {
  bf16 h = __float2bfloat16(f);
  return *reinterpret_cast<unsigned short*>(&h);
}
__device__ __forceinline__ float su2f(unsigned short u) {
  bf16 t; *reinterpret_cast<unsigned short*>(&t) = u; return __bfloat162float(t);
}
#define MFMA16 __builtin_amdgcn_mfma_f32_16x16x32_bf16

// ---- conv weight prep helper: (CO=64, CI, 9) f32 -> fragment-linear bf16 ----
__device__ __forceinline__ void wprep_one(
    int d, const float* __restrict__ src, bf16* __restrict__ dst, int CI)
{
  int j   = d & 7;
  int l   = (d >> 3) & 63;
  int wid = (d >> 9) & 3;
  int r   = d >> 11;
  int nchi = CI >> 5;
  int chi = r % nchi, t = r / nchi;
  int co = wid * 16 + (l & 15);
  int ci = chi * 32 + 8 * (l >> 4) + j;
  dst[d] = __float2bfloat16(src[(co * CI + ci) * 9 + t]);
}

// ---- merged prep: all conv wfrags + fc + mlpT + rcT/rcb in ONE dispatch ----
__global__ __launch_bounds__(256) void k_prep_all(
    const float* __restrict__ conv_w,
    const float* __restrict__ cat_w0, const float* __restrict__ cat_w1,
    const float* __restrict__ cat_w2,
    const float* __restrict__ fc_w, const float* __restrict__ mlp_w,
    const float* __restrict__ regw, const float* __restrict__ regb,
    const float* __restrict__ clsw, const float* __restrict__ clsb,
    bf16* __restrict__ wtr0, bf16* __restrict__ wtr1, bf16* __restrict__ wtr2,
    bf16* __restrict__ wcat0, bf16* __restrict__ wcat1, bf16* __restrict__ wcat2,
    bf16* __restrict__ wfc, bf16* __restrict__ mlpwT,
    bf16* __restrict__ rcT, float* __restrict__ rcb)
{
  int d = blockIdx.x * 256 + threadIdx.x;
  if (d < 36864)        { wprep_one(d, conv_w,               wtr0, 64); return; }
  d -= 36864;
  if (d < 36864)        { wprep_one(d, conv_w + 36864,       wtr1, 64); return; }
  d -= 36864;
  if (d < 36864)        { wprep_one(d, conv_w + 2*36864,     wtr2, 64); return; }
  d -= 36864;
  if (d < 36864)        { wprep_one(d, cat_w0, wcat0, 64);  return; }
  d -= 36864;
  if (d < 73728)        { wprep_one(d, cat_w1, wcat1, 128); return; }
  d -= 73728;
  if (d < 110592)       { wprep_one(d, cat_w2, wcat2, 192); return; }
  d -= 110592;
  if (d < 147456) {     // fc: [72][4][64][8]; k = s*64 + c ; src (c*36+s, 64)
    int j    = d & 7;
    int l    = (d >> 3) & 63;
    int tile = (d >> 9) & 3;
    int kk   = d >> 11;
    int cout = tile * 16 + (l & 15);
    int k    = kk * 32 + 8 * (l >> 4) + j;
    int c = k & 63, s = k >> 6;
    wfc[d] = __float2bfloat16(fc_w[(c * kS + s) * kC + cout]);
    return;
  }
  d -= 147456;
  if (d < 4096) {       // mlpwT [cout][cin]
    int co = d >> 6, ci = d & 63;
    mlpwT[d] = __float2bfloat16(mlp_w[ci * 64 + co]);
    return;
  }
  d -= 4096;
  if (d < 5120) {       // rcT [80][64]
    int o = d >> 6, ci = d & 63;
    float v = (o < 76) ? regw[ci * 76 + o] : (o < 78 ? clsw[ci * 2 + (o - 76)] : 0.f);
    rcT[d] = __float2bfloat16(v);
    if (d < 80) rcb[d] = (d < 76) ? regb[d] : (d < 78 ? clsb[d - 76] : 0.f);
  }
}

// ---- merged fmap transpose for ALL 3 stages: [b][c][h][w] f32 -> [b][y][x][c] bf16 ----
__global__ __launch_bounds__(256) void k_transpose3(
    const float* __restrict__ x2, const float* __restrict__ x1, const float* __restrict__ x0,
    bf16* __restrict__ f0, bf16* __restrict__ f1, bf16* __restrict__ f2)
{
  __shared__ float tile[64][65];
  int byA = blockIdx.x;
  const float* src; bf16* dst; int h, w;
  if (byA < kB*10)            { src = x2; dst = f0; h = 10; w = 25;  }
  else if (byA < kB*30)       { src = x1; dst = f1; h = 20; w = 50;  byA -= kB*10; }
  else                        { src = x0; dst = f2; h = 40; w = 100; byA -= kB*30; }
  const int b = byA / h, y = byA % h;
  const int lane = threadIdx.x & 63, wq = threadIdx.x >> 6;
  for (int x0i = 0; x0i < w; x0i += 64) {
    #pragma unroll
    for (int cc = 0; cc < 16; ++cc) {
      int c = wq * 16 + cc;
      int x = x0i + lane;
      if (x < w) tile[c][lane] = src[((size_t)(b*kC + c)*h + y)*w + x];
    }
    __syncthreads();
    #pragma unroll
    for (int xx = 0; xx < 16; ++xx) {
      int x = x0i + wq * 16 + xx;
      if (x < w) dst[((size_t)(b*h + y)*w + x)*kC + lane] = __float2bfloat16(tile[lane][wq*16 + xx]);
    }
    __syncthreads();
  }
}

// ---- merged key/value for ALL 3 stages, reading COALESCED channel vectors from fmapT ----
// block = 4 positions x 64 lanes; grid = 3*kB*64 = 6144
__global__ __launch_bounds__(256) void k_keyval3(
    const bf16* __restrict__ f0, const bf16* __restrict__ f1, const bf16* __restrict__ f2,
    const float* __restrict__ fkeyw, const float* __restrict__ bnk,
    const float* __restrict__ fvalw, const float* __restrict__ fvalb,
    bf16* __restrict__ k0, bf16* __restrict__ v0,
    bf16* __restrict__ k1, bf16* __restrict__ v1,
    bf16* __restrict__ k2, bf16* __restrict__ v2)
{
  const int tid = threadIdx.x, lane = tid & 63, grp = tid >> 6;
  int blk = blockIdx.x;
  const int stage = blk / (kB*64);
  blk -= stage * (kB*64);
  const bf16* fmapT; bf16 *key_pc, *val_ck; int h, w;
  if (stage == 0)      { fmapT = f0; key_pc = k0; val_ck = v0; h = 10; w = 25;  }
  else if (stage == 1) { fmapT = f1; key_pc = k1; val_ck = v1; h = 20; w = 50;  }
  else                 { fmapT = f2; key_pc = k2; val_ck = v2; h = 40; w = 100; }
  const int b = blk >> 6, pg = blk & 63;
  const int pos = pg * 4 + grp;
  __shared__ float fv[4][64];
  const bool valid = (pos < 250);
  if (valid) {
    int i = pos / 25, j = pos % 25;
    int yi = (i * h) / 10, xj = (j * w) / 25;
    fv[grp][lane] = b2f(fmapT[((size_t)(b*h + yi)*w + xj)*kC + lane]);
  }
  __syncthreads();
  if (valid) {
    float ka = 0.f, va = 0.f;
    const float* kr = fkeyw + lane * kC;
    const float* vr = fvalw + lane * kC;
    #pragma unroll 8
    for (int c = 0; c < kC; ++c) { float f = fv[grp][c]; ka += f * kr[c]; va += f * vr[c]; }
    float g = bnk[lane], bb = bnk[kC + lane];
    float m = bnk[2*kC + lane], v = bnk[3*kC + lane];
    float sc = g / sqrtf(v + 1e-5f), sh = bb - m * sc;
    key_pc[((size_t)b*256 + pos)*kC + lane] = __float2bfloat16(fmaxf(ka*sc + sh, 0.f));
    val_ck[((size_t)b*kC + lane)*256 + pos] = __float2bfloat16(va + fvalb[lane]);
  } else {
    key_pc[((size_t)b*256 + pos)*kC + lane] = __float2bfloat16(0.f);
    val_ck[((size_t)b*kC + lane)*256 + pos] = __float2bfloat16(0.f);
  }
}

// ---- fused grid_sample + conv1d(k9,pad4) MFMA + BN + ReLU ; 2 rows/block ----
// wave = (row r2, cout-pair cp): 1 ds_read feeds 2 MFMA (ds:MFMA = 1:2)
__global__ __launch_bounds__(256) void k_trans(
    const bf16* __restrict__ fmapT, int h, int w,
    const float* __restrict__ pfeat0, const float* __restrict__ pfeatw, int stage,
    const bf16* __restrict__ wfrag,     // fragment-linear [9][2][4][64][8]
    const float* __restrict__ bnp,      // (4,64) f32
    bf16* __restrict__ transOut)        // (6144,36,64) bf16
{
  __shared__ __align__(16) bf16 poolT[2][56][64];
  __shared__ float bsc[kC], bsh[kC];
  const int tid = threadIdx.x;
  const int row0 = blockIdx.x * 2, b = row0 / kP;

  if (tid < kC) {
    float g = bnp[tid], bb = bnp[kC + tid];
    float m = bnp[2*kC + tid], v = bnp[3*kC + tid];
    float sc = g / sqrtf(v + 1e-5f);
    bsc[tid] = sc; bsh[tid] = bb - m * sc;
  }
  unsigned int* pz = (unsigned int*)&poolT[0][0][0];
  for (int e = tid; e < 2*56*32; e += 256) pz[e] = 0u;
  __syncthreads();

  const int lc = tid & 7;
  for (int idx = tid >> 3; idx < 2*kS; idx += 32) {
    int r2 = idx / kS, s = idx % kS;
    int row = row0 + r2, p = row % kP;
    float px = (stage == 0) ? pfeat0[p*kS + (kS-1-s)] : pfeatw[row*kS + (kS-1-s)];
    float fy = 1.0f - (float)d_SX[kS-1-s] / 71.0f;
    float x = px * (float)(w - 1);
    float y = fy * (float)(h - 1);
    float x0f = floorf(x), y0f = floorf(y);
    float wx = x - x0f, wy = y - y0f;
    int xi = (int)x0f, yi = (int)y0f;
    float a8[8];
    #pragma unroll
    for (int j = 0; j < 8; ++j) a8[j] = 0.f;
    #pragma unroll
    for (int cy = 0; cy < 2; ++cy) {
      #pragma unroll
      for (int cx = 0; cx < 2; ++cx) {
        int xx = xi + cx, yy = yi + cy;
        if (xx >= 0 && xx < w && yy >= 0 && yy < h) {
          float wgt = (cx ? wx : 1.f - wx) * (cy ? wy : 1.f - wy);
          short8v v = *(const short8v*)&fmapT[((size_t)(b*h + yy)*w + xx)*kC + lc*8];
          #pragma unroll
          for (int j = 0; j < 8; ++j)
            a8[j] += su2f((unsigned short)v[j]) * wgt;
        }
      }
    }
    uint4 pk;
    pk.x = (unsigned)f2bu(a8[0]) | ((unsigned)f2bu(a8[1]) << 16);
    pk.y = (unsigned)f2bu(a8[2]) | ((unsigned)f2bu(a8[3]) << 16);
    pk.z = (unsigned)f2bu(a8[4]) | ((unsigned)f2bu(a8[5]) << 16);
    pk.w = (unsigned)f2bu(a8[6]) | ((unsigned)f2bu(a8[7]) << 16);
    int lr = s + 4;
    *reinterpret_cast<uint4*>(&poolT[r2][lr][((lc + lr) & 7)*8]) = pk;
  }
  __syncthreads();

  const int wv = tid >> 6, lane = tid & 63;
  const int r2 = wv & 1, cp = wv >> 1;    // wave = (row, cout-pair)
  const int lm = lane & 15, lq = lane >> 4;
  float4v acc[2][3] = {{{0,0,0,0},{0,0,0,0},{0,0,0,0}},{{0,0,0,0},{0,0,0,0},{0,0,0,0}}};
  #pragma unroll
  for (int t = 0; t < 9; ++t) {
    #pragma unroll
    for (int chi = 0; chi < 2; ++chi) {
      short8v a0 = *(const short8v*)&wfrag[(((t*2 + chi)*4 + cp*2 + 0)*64 + lane)*8];
      short8v a1 = *(const short8v*)&wfrag[(((t*2 + chi)*4 + cp*2 + 1)*64 + lane)*8];
      #pragma unroll
      for (int nt = 0; nt < 3; ++nt) {
        int rr = nt*16 + lm + t;
        int sl = chi*4 + lq;
        short8v bb = *(const short8v*)&poolT[r2][rr][((sl + rr) & 7)*8];
        acc[0][nt] = MFMA16(a0, bb, acc[0][nt], 0, 0, 0);
        acc[1][nt] = MFMA16(a1, bb, acc[1][nt], 0, 0, 0);
      }
    }
  }
  #pragma unroll
  for (int c2 = 0; c2 < 2; ++c2) {
    const int c4 = (cp*2 + c2)*16 + 4*lq;
    float s0 = bsc[c4], s1 = bsc[c4+1], s2 = bsc[c4+2], s3 = bsc[c4+3];
    float h0 = bsh[c4], h1 = bsh[c4+1], h2 = bsh[c4+2], h3 = bsh[c4+3];
    #pragma unroll
    for (int nt = 0; nt < 3; ++nt) {
      int s = nt*16 + lm;
      if (s < kS) {
        uint2 pk;
        pk.x = (unsigned)f2bu(fmaxf(acc[c2][nt][0]*s0 + h0, 0.f))
             | ((unsigned)f2bu(fmaxf(acc[c2][nt][1]*s1 + h1, 0.f)) << 16);
        pk.y = (unsigned)f2bu(fmaxf(acc[c2][nt][2]*s2 + h2, 0.f))
             | ((unsigned)f2bu(fmaxf(acc[c2][nt][3]*s3 + h3, 0.f)) << 16);
        *reinterpret_cast<uint2*>(&transOut[((size_t)(row0+r2)*kS + s)*kC + c4]) = pk;
      }
    }
  }
}

// ---- concat(trans[0..st]) -> conv1d(k9,pad4) via MFMA + BN + ReLU ; 2 rows/block ----
template<int NCI>
__global__ __launch_bounds__(256) void k_catconv(
    const bf16* __restrict__ t0, const bf16* __restrict__ t1, const bf16* __restrict__ t2,
    const bf16* __restrict__ wfrag,   // [9][NCI/32][4][64][8]
    const float* __restrict__ bnp, bf16* __restrict__ catOut)
{
  constexpr int CB = NCI/8;           // slots per row
  __shared__ __align__(16) bf16 poolT[2][56][NCI];
  __shared__ float bsc[kC], bsh[kC];
  const int tid = threadIdx.x;
  const int row0 = blockIdx.x * 2;
  if (tid < kC) {
    float g = bnp[tid], bb = bnp[kC + tid];
    float m = bnp[2*kC + tid], v = bnp[3*kC + tid];
    float sc = g / sqrtf(v + 1e-5f);
    bsc[tid] = sc; bsh[tid] = bb - m * sc;
  }
  unsigned int* pz = (unsigned int*)&poolT[0][0][0];
  for (int e = tid; e < 2*56*NCI/2; e += 256) pz[e] = 0u;
  __syncthreads();

  const bf16* tb[3] = {t0, t1, t2};
  for (int cc = tid; cc < 2*kS*CB; cc += 256) {
    int r2 = cc / (kS*CB), rem = cc % (kS*CB);
    int s = rem / CB, cb = rem % CB;
    int ch = cb * 8, i = ch >> 6, c = ch & 63;
    const short8v* src = (const short8v*)&tb[i][((size_t)(row0+r2)*kS + s)*kC + c];
    int lr = s + 4;
    int sl = (cb & ~7) | ((cb + lr) & 7);
    *(short8v*)&poolT[r2][lr][sl*8] = *src;
  }
  __syncthreads();

  const int wv = tid >> 6, lane = tid & 63;
  const int r2 = wv & 1, cp = wv >> 1;    // wave = (row, cout-pair)
  const int lm = lane & 15, lq = lane >> 4;
  float4v acc[2][3] = {{{0,0,0,0},{0,0,0,0},{0,0,0,0}},{{0,0,0,0},{0,0,0,0},{0,0,0,0}}};
  #pragma unroll
  for (int t = 0; t < 9; ++t) {
    #pragma unroll
    for (int chi = 0; chi < NCI/32; ++chi) {
      short8v a0 = *(const short8v*)&wfrag[(((t*(NCI/32) + chi)*4 + cp*2 + 0)*64 + lane)*8];
      short8v a1 = *(const short8v*)&wfrag[(((t*(NCI/32) + chi)*4 + cp*2 + 1)*64 + lane)*8];
      #pragma unroll
      for (int nt = 0; nt < 3; ++nt) {
        int rr = nt*16 + lm + t;
        int sl0 = chi*4 + lq;
        int sl = (sl0 & ~7) | ((sl0 + rr) & 7);
        short8v bb = *(const short8v*)&poolT[r2][rr][sl*8];
        acc[0][nt] = MFMA16(a0, bb, acc[0][nt], 0, 0, 0);
        acc[1][nt] = MFMA16(a1, bb, acc[1][nt], 0, 0, 0);
      }
    }
  }
  #pragma unroll
  for (int c2 = 0; c2 < 2; ++c2) {
    const int c4 = (cp*2 + c2)*16 + 4*lq;
    float s0 = bsc[c4], s1 = bsc[c4+1], s2 = bsc[c4+2], s3 = bsc[c4+3];
    float h0 = bsh[c4], h1 = bsh[c4+1], h2 = bsh[c4+2], h3 = bsh[c4+3];
    #pragma unroll
    for (int nt = 0; nt < 3; ++nt) {
      int s = nt*16 + lm;
      if (s < kS) {
        uint2 pk;
        pk.x = (unsigned)f2bu(fmaxf(acc[c2][nt][0]*s0 + h0, 0.f))
             | ((unsigned)f2bu(fmaxf(acc[c2][nt][1]*s1 + h1, 0.f)) << 16);
        pk.y = (unsigned)f2bu(fmaxf(acc[c2][nt][2]*s2 + h2, 0.f))
             | ((unsigned)f2bu(fmaxf(acc[c2][nt][3]*s3 + h3, 0.f)) << 16);
        *reinterpret_cast<uint2*>(&catOut[((size_t)(row0+r2)*kS + s)*kC + c4]) = pk;
      }
    }
  }
}

// ---- mega tail: fc+LN -> attn(QK^T, softmax, PV, residual) -> mlp+heads -> geometry/epi ----
__global__ __launch_bounds__(256) void k_tail(
    const bf16* __restrict__ catOut, const bf16* __restrict__ wfc,
    const float* __restrict__ fcb, const float* __restrict__ lng, const float* __restrict__ lnb,
    const bf16* __restrict__ key_pc, const bf16* __restrict__ val_ck,
    const float* __restrict__ fqw, const float* __restrict__ fqb,
    const float* __restrict__ aww, const float* __restrict__ awb,
    const bf16* __restrict__ mlpwT, const float* __restrict__ mlpb,
    const bf16* __restrict__ rcT, const float* __restrict__ rcb,
    const float* __restrict__ priors0, const float* __restrict__ priw_in, int stage,
    float* __restrict__ out, float* __restrict__ priw_out, float* __restrict__ pfeat_out)
{
  __shared__ __align__(16) float partS[4][16][68];  // fc partials, reused as S[16][264]
  __shared__ __align__(16) float roiL[12][68];
  __shared__ __align__(16) bf16 q[16][72];
  __shared__ __align__(16) bf16 P[16][264];
  __shared__ float rsum[16];
  __shared__ __align__(16) bf16 r2b[16][72];
  __shared__ __align__(16) bf16 h1l[16][72];
  __shared__ __align__(16) bf16 h2l[16][72];
  __shared__ float regc[12][84];
  __shared__ float ev[12][8];

  const int tid = threadIdx.x;
  const int blk = blockIdx.x, b = blk >> 4, tile = blk & 15;
  const int p0 = tile * 12;
  const int lane = tid & 63, wq = tid >> 6;
  const int lm = lane & 15, lq = lane >> 4;
  float (*S)[264] = (float (*)[264])&partS[0][0][0];

  { unsigned* z1 = (unsigned*)&q[0][0];
    for (int e = tid; e < 16*72/2; e += 256) z1[e] = 0u;
    unsigned* z2 = (unsigned*)&r2b[0][0];
    for (int e = tid; e < 16*72/2; e += 256) z2[e] = 0u; }

  {
    float4v fa[4] = {{0,0,0,0},{0,0,0,0},{0,0,0,0},{0,0,0,0}};
    int r0c = p0 + lm; if (r0c > p0 + 11) r0c = p0 + 11;
    const bf16* bb0 = catOut + (size_t)(b*kP + r0c) * 2304 + lq * 8;
    for (int kk = wq * 18; kk < wq * 18 + 18; ++kk) {
      short8v bf0 = *(const short8v*)&bb0[kk * 32];
      #pragma unroll
      for (int t = 0; t < 4; ++t) {
        short8v afrag = *(const short8v*)&wfc[((kk*4 + t)*64 + lane)*8];
        fa[t] = MFMA16(afrag, bf0, fa[t], 0, 0, 0);
      }
    }
    #pragma unroll
    for (int t = 0; t < 4; ++t)
      *(float4v*)&partS[wq][lm][t*16 + lq*4] = fa[t];
  }
  __syncthreads();
  for (int r = wq; r < 12; r += 4) {
    float v = partS[0][r][lane] + partS[1][r][lane] + partS[2][r][lane] + partS[3][r][lane]
            + fcb[lane];
    float s1 = v, s2 = v * v;
    #pragma unroll
    for (int m = 32; m; m >>= 1) { s1 += __shfl_xor(s1, m, 64); s2 += __shfl_xor(s2, m, 64); }
    float mu = s1 * (1.f/64.f);
    float var = s2 * (1.f/64.f) - mu * mu;
    float y = fmaxf((v - mu) * rsqrtf(var + 1e-5f) * lng[lane] + lnb[lane], 0.f);
    roiL[r][lane] = y;
    int p = p0 + r;
    q[r][lane] = __float2bfloat16(fmaxf(y * fqw[p] + fqb[p], 0.f));
  }
  __syncthreads();

  {
    float4v acc[4] = {{0,0,0,0},{0,0,0,0},{0,0,0,0},{0,0,0,0}};
    #pragma unroll
    for (int ks = 0; ks < 2; ++ks) {
      short8v aq0 = *(const short8v*)&q[lm][ks*32 + 8*lq];
      #pragma unroll
      for (int nt = 0; nt < 4; ++nt) {
        int pos = (wq*4 + nt)*16 + lm;
        short8v bk = *(const short8v*)&key_pc[((size_t)(b*256 + pos))*kC + ks*32 + 8*lq];
        acc[nt] = MFMA16(aq0, bk, acc[nt], 0, 0, 0);
      }
    }
    #pragma unroll
    for (int nt = 0; nt < 4; ++nt)
      #pragma unroll
      for (int r = 0; r < 4; ++r)
        S[lq*4 + r][(wq*4 + nt)*16 + lm] = acc[nt][r] * 0.125f;
  }
  __syncthreads();

  {
    int r = tid >> 4, g = tid & 15;
    float mx = -1e30f;
    #pragma unroll 16
    for (int k = 0; k < 16; ++k) { int c = g + 16*k; if (c < 250) mx = fmaxf(mx, S[r][c]); }
    #pragma unroll
    for (int m = 1; m < 16; m <<= 1) mx = fmaxf(mx, __shfl_xor(mx, m, 64));
    float sum = 0.f;
    #pragma unroll 16
    for (int k = 0; k < 16; ++k) {
      int c = g + 16*k;
      float e = 0.f;
      if (c < 250) { e = expf(S[r][c] - mx); sum += e; }
      P[r][c] = __float2bfloat16(e);
    }
    #pragma unroll
    for (int m = 1; m < 16; m <<= 1) sum += __shfl_xor(sum, m, 64);
    if (g == 0) rsum[r] = sum;
  }
  __syncthreads();

  {
    float4v acc = {0,0,0,0};
    #pragma unroll
    for (int ks = 0; ks < 8; ++ks) {
      short8v bv = *(const short8v*)&val_ck[((size_t)(b*kC + wq*16 + lm))*256 + ks*32 + 8*lq];
      short8v ap0 = *(const short8v*)&P[lm][ks*32 + 8*lq];
      acc = MFMA16(ap0, bv, acc, 0, 0, 0);
    }
    #pragma unroll
    for (int r = 0; r < 4; ++r) {
      int pl = lq*4 + r;
      if (pl < 12) {
        int p = p0 + pl, c = wq*16 + lm;
        float ctx = acc[r] / rsum[pl];
        r2b[pl][c] = __float2bfloat16(roiL[pl][c] + ctx * aww[p] + awb[p]);
      }
    }
  }
  __syncthreads();

  {
    float4v acc = {0,0,0,0};
    #pragma unroll
    for (int ks = 0; ks < 2; ++ks) {
      short8v a0 = *(const short8v*)&r2b[lm][ks*32 + 8*lq];
      short8v bw = *(const short8v*)&mlpwT[(wq*16 + lm)*kC + ks*32 + 8*lq];
      acc = MFMA16(a0, bw, acc, 0, 0, 0);
    }
    #pragma unroll
    for (int r = 0; r < 4; ++r) {
      int rw = lq*4 + r, col = wq*16 + lm;
      h1l[rw][col] = __float2bfloat16(fmaxf(acc[r] + mlpb[col], 0.f));
    }
  }
  __syncthreads();
  {
    float4v acc = {0,0,0,0};
    #pragma unroll
    for (int ks = 0; ks < 2; ++ks) {
      short8v a0 = *(const short8v*)&h1l[lm][ks*32 + 8*lq];
      short8v bw = *(const short8v*)&mlpwT[(wq*16 + lm)*kC + ks*32 + 8*lq];
      acc = MFMA16(a0, bw, acc, 0, 0, 0);
    }
    #pragma unroll
    for (int r = 0; r < 4; ++r) {
      int rw = lq*4 + r, col = wq*16 + lm;
      h2l[rw][col] = __float2bfloat16(fmaxf(acc[r] + mlpb[col], 0.f));
    }
  }
  __syncthreads();
  for (int ntile = wq; ntile < 5; ntile += 4) {
    float4v acc = {0,0,0,0};
    #pragma unroll
    for (int ks = 0; ks < 2; ++ks) {
      short8v a0 = *(const short8v*)&h2l[lm][ks*32 + 8*lq];
      short8v bw = *(const short8v*)&rcT[(ntile*16 + lm)*kC + ks*32 + 8*lq];
      acc = MFMA16(a0, bw, acc, 0, 0, 0);
    }
    #pragma unroll
    for (int r = 0; r < 4; ++r) {
      int rw = lq*4 + r, col = ntile*16 + lm;
      if (rw < 12) regc[rw][col] = acc[r] + rcb[col];
    }
  }
  __syncthreads();

  if (tid < 12) {
    int r = tid, p = p0 + r, grow = b*kP + p;
    float pr2, pr3, pr4;
    if (stage == 0) {
      pr2 = priors0[p*78 + 2]; pr3 = priors0[p*78 + 3]; pr4 = priors0[p*78 + 4];
    } else {
      const float* pw = priw_in + (size_t)grow * 78;
      pr2 = pw[2]; pr3 = pw[3]; pr4 = pw[4];
    }
    float p2 = pr2 + regc[r][0], p3 = pr3 + regc[r][1];
    float p4 = pr4 + regc[r][2], p5 = regc[r][3];
    ev[r][0] = p2; ev[r][1] = p3; ev[r][2] = p4; ev[r][3] = p5;
    ev[r][4] = 320.f / tanf(p4 * kPI + 1e-5f);
    ev[r][5] = regc[r][76]; ev[r][6] = regc[r][77];
  }
  __syncthreads();
  for (int e = tid; e < 12*78; e += 256) {
    int r = e / 78, o = e % 78;
    int p = p0 + r, grow = b*kP + p;
    float p2 = ev[r][0], p3 = ev[r][1], t320 = ev[r][4];
    float g = 0.f, v;
    if (o >= 6) g = (p3 * 799.f + ((float)(o-6) / 71.f - p2) * t320) / 799.f;
    if      (o == 0) v = ev[r][5];
    else if (o == 1) v = ev[r][6];
    else if (o == 2) v = p2;
    else if (o == 3) v = p3;
    else if (o == 4) v = ev[r][2];
    else if (o == 5) v = ev[r][3];
    else             v = g + regc[r][4 + (o - 6)];
    out[((size_t)(stage*kB + b)*kP + p) * 78 + o] = v;
    if (stage < 2) priw_out[(size_t)grow*78 + o] = (o < 6) ? v : g;
  }
  if (stage < 2) {
    for (int e = tid; e < 12*kS; e += 256) {
      int r = e / kS, si = e % kS;
      int grow = b*kP + p0 + r;
      float p2 = ev[r][0], p3 = ev[r][1], t320 = ev[r][4];
      pfeat_out[(size_t)grow*kS + si] =
          (p3 * 799.f + ((float)d_SX[si] / 71.f - p2) * t320) / 799.f;
    }
  }
}

extern "C" void kernel_launch(void* const* d_in, const int* in_sizes, int n_in,
                              void* d_out, int out_size, void* d_ws, size_t ws_size,
                              hipStream_t stream) {
  const float* x0      = (const float*)d_in[0];
  const float* x1      = (const float*)d_in[1];
  const float* x2      = (const float*)d_in[2];
  const float* priors0 = (const float*)d_in[3];
  const float* pfeat0  = (const float*)d_in[4];
  const float* conv_w  = (const float*)d_in[5];
  const float* bn_conv = (const float*)d_in[6];
  const float* cat_w[3]= {(const float*)d_in[7], (const float*)d_in[8], (const float*)d_in[9]};
  const float* bn_cat  = (const float*)d_in[10];
  const float* fkey_w  = (const float*)d_in[11];
  const float* bn_key  = (const float*)d_in[12];
  const float* fval_w  = (const float*)d_in[13];
  const float* fval_b  = (const float*)d_in[14];
  const float* fq_w    = (const float*)d_in[15];
  const float* fq_b    = (const float*)d_in[16];
  const float* attnW_w = (const float*)d_in[17];
  const float* attnW_b = (const float*)d_in[18];
  const float* fc_w    = (const float*)d_in[19];
  const float* fc_b    = (const float*)d_in[20];
  const float* ln_g    = (const float*)d_in[21];
  const float* ln_b    = (const float*)d_in[22];
  const float* mlp_w   = (const float*)d_in[23];
  const float* mlp_b   = (const float*)d_in[24];
  const float* reg_w   = (const float*)d_in[25];
  const float* reg_b   = (const float*)d_in[26];
  const float* cls_w   = (const float*)d_in[27];
  const float* cls_b   = (const float*)d_in[28];
  float* out = (float*)d_out;

  char* ws = (char*)d_ws;
  size_t off = 0;
  auto alloc = [&](size_t bytes) { void* pp = ws + off; off += (bytes + 255) & ~(size_t)255; return pp; };
  bf16* trans[3];
  for (int i = 0; i < 3; ++i) trans[i] = (bf16*)alloc((size_t)kRows * 2304 * sizeof(bf16));
  bf16*  catout = (bf16*) alloc((size_t)kRows * 2304 * sizeof(bf16));
  bf16*  key_pc[3]; bf16* val_ck[3];
  for (int i = 0; i < 3; ++i) {
    key_pc[i] = (bf16*)alloc((size_t)kB * 256 * kC * sizeof(bf16));
    val_ck[i] = (bf16*)alloc((size_t)kB * kC * 256 * sizeof(bf16));
  }
  float* priwA  = (float*)alloc((size_t)kRows * 78 * sizeof(float));
  float* priwB  = (float*)alloc((size_t)kRows * 78 * sizeof(float));
  float* pfw    = (float*)alloc((size_t)kRows * kS * sizeof(float));
  bf16* wtr[3], *wcat[3];
  const int catCI[3] = {64, 128, 192};
  for (int i = 0; i < 3; ++i) wtr[i]  = (bf16*)alloc((size_t)64*64*9 * sizeof(bf16));
  for (int i = 0; i < 3; ++i) wcat[i] = (bf16*)alloc((size_t)64*catCI[i]*9 * sizeof(bf16));
  bf16* wfc    = (bf16*)alloc((size_t)2304*64 * sizeof(bf16));
  bf16* mlpwT  = (bf16*)alloc((size_t)64*64 * sizeof(bf16));
  bf16* rcT    = (bf16*)alloc((size_t)80*64 * sizeof(bf16));
  float* rcb   = (float*)alloc((size_t)80 * sizeof(float));
  const int hd[3] = {10, 20, 40}, wd[3] = {25, 50, 100};
  bf16* fmapT[3];
  for (int i = 0; i < 3; ++i)
    fmapT[i] = (bf16*)alloc((size_t)kB * hd[i] * wd[i] * kC * sizeof(bf16));
  (void)ws_size; (void)in_sizes; (void)n_in; (void)out_size;

  // merged one-time preps: 3 dispatches
  k_prep_all<<<(488448 + 255)/256, 256, 0, stream>>>(
      conv_w, cat_w[0], cat_w[1], cat_w[2], fc_w, mlp_w, reg_w, reg_b, cls_w, cls_b,
      wtr[0], wtr[1], wtr[2], wcat[0], wcat[1], wcat[2], wfc, mlpwT, rcT, rcb);
  k_transpose3<<<kB*70, 256, 0, stream>>>(x2, x1, x0, fmapT[0], fmapT[1], fmapT[2]);
  k_keyval3<<<3*kB*64, 256, 0, stream>>>(fmapT[0], fmapT[1], fmapT[2],
                                         fkey_w, bn_key, fval_w, fval_b,
                                         key_pc[0], val_ck[0], key_pc[1], val_ck[1],
                                         key_pc[2], val_ck[2]);

  for (int st = 0; st < 3; ++st) {
    const int h = hd[st], w = wd[st];
    const float* priw_in  = (st == 1) ? priwA : priwB;   // unused at st==0
    float*       priw_out = (st == 0) ? priwA : priwB;   // ping-pong
    k_trans<<<kRows/2, 256, 0, stream>>>(fmapT[st], h, w, pfeat0, pfw, st,
                                         wtr[st], bn_conv + st*4*kC, trans[st]);
    if (st == 0)
      k_catconv<64><<<kRows/2, 256, 0, stream>>>(trans[0], trans[1], trans[2], wcat[0],
                                                 bn_cat + st*4*kC, catout);
    else if (st == 1)
      k_catconv<128><<<kRows/2, 256, 0, stream>>>(trans[0], trans[1], trans[2], wcat[1],
                                                  bn_cat + st*4*kC, catout);
    else
      k_catconv<192><<<kRows/2, 256, 0, stream>>>(trans[0], trans[1], trans[2], wcat[2],
                                                  bn_cat + st*4*kC, catout);
    k_tail<<<kB*16, 256, 0, stream>>>(catout, wfc, fc_b, ln_g, ln_b,
                                      key_pc[st], val_ck[st], fq_w, fq_b, attnW_w, attnW_b,
                                      mlpwT, mlp_b, rcT, rcb,
                                      priors0, priw_in, st, out, priw_out, pfw);
  }
}

// Round 18
// 390.306 us; speedup vs baseline: 1.5937x; 1.1574x over previous
//
#include <hip/hip_runtime.h>
#include <hip/hip_bf16.h>
#include <math.h>

typedef __hip_bfloat16 bf16;
typedef __attribute__((ext_vector_type(8))) short short8v;   // 8 bf16 (4 VGPRs)
typedef __attribute__((ext_vector_type(4))) float float4v;   // MFMA accumulator

static constexpr int kB = 32;
static constexpr int kP = 192;
static constexpr int kS = 36;
static constexpr int kC = 64;
static constexpr int kRows = kB * kP;   // 6144
static constexpr float kPI = 3.14159265358979323846f;

__device__ __constant__ int d_SX[36] = {
  0,2,4,6,8,10,12,14,16,18,20,22,24,26,28,30,32,34,
  36,38,40,42,44,46,48,50,52,54,56,58,60,62,64,66,68,71};

__device__ __forceinline__ float b2f(bf16 v) { return __bfloat162float(v); }
__device__ __forceinline__ unsigned short f2bu(float f) {
  bf16 h = __float2bfloat16(f);
  return *reinterpret_cast<unsigned short*>(&h);
}
__device__ __forceinline__ float su2f(unsigned short u) {
  bf16 t; *reinterpret_cast<unsigned short*>(&t) = u; return __bfloat162float(t);
}
#define MFMA16 __builtin_amdgcn_mfma_f32_16x16x32_bf16

// ---- conv weight prep helper: (CO=64, CI, 9) f32 -> fragment-linear bf16 ----
__device__ __forceinline__ void wprep_one(
    int d, const float* __restrict__ src, bf16* __restrict__ dst, int CI)
{
  int j   = d & 7;
  int l   = (d >> 3) & 63;
  int wid = (d >> 9) & 3;
  int r   = d >> 11;
  int nchi = CI >> 5;
  int chi = r % nchi, t = r / nchi;
  int co = wid * 16 + (l & 15);
  int ci = chi * 32 + 8 * (l >> 4) + j;
  dst[d] = __float2bfloat16(src[(co * CI + ci) * 9 + t]);
}

// ---- merged prep: conv wfrags + fc + mlpT + rcT/rcb + TRANSPOSED key/val weights ----
// segments: wtr0/1/2 36864 | wcat0 36864 | wcat1 73728 | wcat2 110592 | wfc 147456
//           mlpT 4096 | rc 5120 | fkeyT 4096 | fvalT 4096  => total 496640
__global__ __launch_bounds__(256) void k_prep_all(
    const float* __restrict__ conv_w,
    const float* __restrict__ cat_w0, const float* __restrict__ cat_w1,
    const float* __restrict__ cat_w2,
    const float* __restrict__ fc_w, const float* __restrict__ mlp_w,
    const float* __restrict__ regw, const float* __restrict__ regb,
    const float* __restrict__ clsw, const float* __restrict__ clsb,
    const float* __restrict__ fkeyw, const float* __restrict__ fvalw,
    bf16* __restrict__ wtr0, bf16* __restrict__ wtr1, bf16* __restrict__ wtr2,
    bf16* __restrict__ wcat0, bf16* __restrict__ wcat1, bf16* __restrict__ wcat2,
    bf16* __restrict__ wfc, bf16* __restrict__ mlpwT,
    bf16* __restrict__ rcT, float* __restrict__ rcb,
    float* __restrict__ fkeyT, float* __restrict__ fvalT)
{
  int d = blockIdx.x * 256 + threadIdx.x;
  if (d < 36864)        { wprep_one(d, conv_w,               wtr0, 64); return; }
  d -= 36864;
  if (d < 36864)        { wprep_one(d, conv_w + 36864,       wtr1, 64); return; }
  d -= 36864;
  if (d < 36864)        { wprep_one(d, conv_w + 2*36864,     wtr2, 64); return; }
  d -= 36864;
  if (d < 36864)        { wprep_one(d, cat_w0, wcat0, 64);  return; }
  d -= 36864;
  if (d < 73728)        { wprep_one(d, cat_w1, wcat1, 128); return; }
  d -= 73728;
  if (d < 110592)       { wprep_one(d, cat_w2, wcat2, 192); return; }
  d -= 110592;
  if (d < 147456) {     // fc: [72][4][64][8]; k = s*64 + c ; src (c*36+s, 64)
    int j    = d & 7;
    int l    = (d >> 3) & 63;
    int tile = (d >> 9) & 3;
    int kk   = d >> 11;
    int cout = tile * 16 + (l & 15);
    int k    = kk * 32 + 8 * (l >> 4) + j;
    int c = k & 63, s = k >> 6;
    wfc[d] = __float2bfloat16(fc_w[(c * kS + s) * kC + cout]);
    return;
  }
  d -= 147456;
  if (d < 4096) {       // mlpwT [cout][cin]
    int co = d >> 6, ci = d & 63;
    mlpwT[d] = __float2bfloat16(mlp_w[ci * 64 + co]);
    return;
  }
  d -= 4096;
  if (d < 5120) {       // rcT [80][64]
    int o = d >> 6, ci = d & 63;
    float v = (o < 76) ? regw[ci * 76 + o] : (o < 78 ? clsw[ci * 2 + (o - 76)] : 0.f);
    rcT[d] = __float2bfloat16(v);
    if (d < 80) rcb[d] = (d < 76) ? regb[d] : (d < 78 ? clsb[d - 76] : 0.f);
    return;
  }
  d -= 5120;
  if (d < 4096) {       // fkeyT [c][cout] = fkeyw[cout][c]  (f32, value-identical)
    int c = d >> 6, co = d & 63;
    fkeyT[d] = fkeyw[co * 64 + c];
    return;
  }
  d -= 4096;
  if (d < 4096) {       // fvalT [c][cout]
    int c = d >> 6, co = d & 63;
    fvalT[d] = fvalw[co * 64 + c];
  }
}

// ---- merged fmap transpose for ALL 3 stages: [b][c][h][w] f32 -> [b][y][x][c] bf16 ----
__global__ __launch_bounds__(256) void k_transpose3(
    const float* __restrict__ x2, const float* __restrict__ x1, const float* __restrict__ x0,
    bf16* __restrict__ f0, bf16* __restrict__ f1, bf16* __restrict__ f2)
{
  __shared__ float tile[64][65];
  int byA = blockIdx.x;
  const float* src; bf16* dst; int h, w;
  if (byA < kB*10)            { src = x2; dst = f0; h = 10; w = 25;  }
  else if (byA < kB*30)       { src = x1; dst = f1; h = 20; w = 50;  byA -= kB*10; }
  else                        { src = x0; dst = f2; h = 40; w = 100; byA -= kB*30; }
  const int b = byA / h, y = byA % h;
  const int lane = threadIdx.x & 63, wq = threadIdx.x >> 6;
  for (int x0i = 0; x0i < w; x0i += 64) {
    #pragma unroll
    for (int cc = 0; cc < 16; ++cc) {
      int c = wq * 16 + cc;
      int x = x0i + lane;
      if (x < w) tile[c][lane] = src[((size_t)(b*kC + c)*h + y)*w + x];
    }
    __syncthreads();
    #pragma unroll
    for (int xx = 0; xx < 16; ++xx) {
      int x = x0i + wq * 16 + xx;
      if (x < w) dst[((size_t)(b*h + y)*w + x)*kC + lane] = __float2bfloat16(tile[lane][wq*16 + xx]);
    }
    __syncthreads();
  }
}

// ---- merged key/val for ALL 3 stages: coalesced fmapT reads + COALESCED weight reads ----
// block = 4 positions x 64 lanes; grid = 3*kB*64 = 6144
__global__ __launch_bounds__(256) void k_keyval3(
    const bf16* __restrict__ f0, const bf16* __restrict__ f1, const bf16* __restrict__ f2,
    const float* __restrict__ fkeyT, const float* __restrict__ bnk,
    const float* __restrict__ fvalT, const float* __restrict__ fvalb,
    bf16* __restrict__ k0, bf16* __restrict__ v0,
    bf16* __restrict__ k1, bf16* __restrict__ v1,
    bf16* __restrict__ k2, bf16* __restrict__ v2)
{
  const int tid = threadIdx.x, lane = tid & 63, grp = tid >> 6;
  int blk = blockIdx.x;
  const int stage = blk / (kB*64);
  blk -= stage * (kB*64);
  const bf16* fmapT; bf16 *key_pc, *val_ck; int h, w;
  if (stage == 0)      { fmapT = f0; key_pc = k0; val_ck = v0; h = 10; w = 25;  }
  else if (stage == 1) { fmapT = f1; key_pc = k1; val_ck = v1; h = 20; w = 50;  }
  else                 { fmapT = f2; key_pc = k2; val_ck = v2; h = 40; w = 100; }
  const int b = blk >> 6, pg = blk & 63;
  const int pos = pg * 4 + grp;
  __shared__ float fv[4][64];
  const bool valid = (pos < 250);
  if (valid) {
    int i = pos / 25, j = pos % 25;
    int yi = (i * h) / 10, xj = (j * w) / 25;
    fv[grp][lane] = b2f(fmapT[((size_t)(b*h + yi)*w + xj)*kC + lane]);
  }
  __syncthreads();
  if (valid) {
    float ka = 0.f, va = 0.f;
    #pragma unroll 8
    for (int c = 0; c < kC; ++c) {
      float f = fv[grp][c];
      ka += f * fkeyT[c*64 + lane];    // coalesced: lanes read consecutive f32
      va += f * fvalT[c*64 + lane];
    }
    float g = bnk[lane], bb = bnk[kC + lane];
    float m = bnk[2*kC + lane], v = bnk[3*kC + lane];
    float sc = g / sqrtf(v + 1e-5f), sh = bb - m * sc;
    key_pc[((size_t)b*256 + pos)*kC + lane] = __float2bfloat16(fmaxf(ka*sc + sh, 0.f));
    val_ck[((size_t)b*kC + lane)*256 + pos] = __float2bfloat16(va + fvalb[lane]);
  } else {
    key_pc[((size_t)b*256 + pos)*kC + lane] = __float2bfloat16(0.f);
    val_ck[((size_t)b*kC + lane)*256 + pos] = __float2bfloat16(0.f);
  }
}

// ---- fused grid_sample + conv1d(k9,pad4) MFMA + BN + ReLU ; 2 rows/block ----
// wave = (row r2, cout-pair cp): 1 ds_read feeds 2 MFMA (ds:MFMA = 1:2)
__global__ __launch_bounds__(256) void k_trans(
    const bf16* __restrict__ fmapT, int h, int w,
    const float* __restrict__ pfeat0, const float* __restrict__ pfeatw, int stage,
    const bf16* __restrict__ wfrag,     // fragment-linear [9][2][4][64][8]
    const float* __restrict__ bnp,      // (4,64) f32
    bf16* __restrict__ transOut)        // (6144,36,64) bf16
{
  __shared__ __align__(16) bf16 poolT[2][56][64];
  __shared__ float bsc[kC], bsh[kC];
  const int tid = threadIdx.x;
  const int row0 = blockIdx.x * 2, b = row0 / kP;

  if (tid < kC) {
    float g = bnp[tid], bb = bnp[kC + tid];
    float m = bnp[2*kC + tid], v = bnp[3*kC + tid];
    float sc = g / sqrtf(v + 1e-5f);
    bsc[tid] = sc; bsh[tid] = bb - m * sc;
  }
  unsigned int* pz = (unsigned int*)&poolT[0][0][0];
  for (int e = tid; e < 2*56*32; e += 256) pz[e] = 0u;
  __syncthreads();

  const int lc = tid & 7;
  for (int idx = tid >> 3; idx < 2*kS; idx += 32) {
    int r2 = idx / kS, s = idx % kS;
    int row = row0 + r2, p = row % kP;
    float px = (stage == 0) ? pfeat0[p*kS + (kS-1-s)] : pfeatw[row*kS + (kS-1-s)];
    float fy = 1.0f - (float)d_SX[kS-1-s] / 71.0f;
    float x = px * (float)(w - 1);
    float y = fy * (float)(h - 1);
    float x0f = floorf(x), y0f = floorf(y);
    float wx = x - x0f, wy = y - y0f;
    int xi = (int)x0f, yi = (int)y0f;
    float a8[8];
    #pragma unroll
    for (int j = 0; j < 8; ++j) a8[j] = 0.f;
    #pragma unroll
    for (int cy = 0; cy < 2; ++cy) {
      #pragma unroll
      for (int cx = 0; cx < 2; ++cx) {
        int xx = xi + cx, yy = yi + cy;
        if (xx >= 0 && xx < w && yy >= 0 && yy < h) {
          float wgt = (cx ? wx : 1.f - wx) * (cy ? wy : 1.f - wy);
          short8v v = *(const short8v*)&fmapT[((size_t)(b*h + yy)*w + xx)*kC + lc*8];
          #pragma unroll
          for (int j = 0; j < 8; ++j)
            a8[j] += su2f((unsigned short)v[j]) * wgt;
        }
      }
    }
    uint4 pk;
    pk.x = (unsigned)f2bu(a8[0]) | ((unsigned)f2bu(a8[1]) << 16);
    pk.y = (unsigned)f2bu(a8[2]) | ((unsigned)f2bu(a8[3]) << 16);
    pk.z = (unsigned)f2bu(a8[4]) | ((unsigned)f2bu(a8[5]) << 16);
    pk.w = (unsigned)f2bu(a8[6]) | ((unsigned)f2bu(a8[7]) << 16);
    int lr = s + 4;
    *reinterpret_cast<uint4*>(&poolT[r2][lr][((lc + lr) & 7)*8]) = pk;
  }
  __syncthreads();

  const int wv = tid >> 6, lane = tid & 63;
  const int r2 = wv & 1, cp = wv >> 1;    // wave = (row, cout-pair)
  const int lm = lane & 15, lq = lane >> 4;
  float4v acc[2][3] = {{{0,0,0,0},{0,0,0,0},{0,0,0,0}},{{0,0,0,0},{0,0,0,0},{0,0,0,0}}};
  #pragma unroll
  for (int t = 0; t < 9; ++t) {
    #pragma unroll
    for (int chi = 0; chi < 2; ++chi) {
      short8v a0 = *(const short8v*)&wfrag[(((t*2 + chi)*4 + cp*2 + 0)*64 + lane)*8];
      short8v a1 = *(const short8v*)&wfrag[(((t*2 + chi)*4 + cp*2 + 1)*64 + lane)*8];
      #pragma unroll
      for (int nt = 0; nt < 3; ++nt) {
        int rr = nt*16 + lm + t;
        int sl = chi*4 + lq;
        short8v bb = *(const short8v*)&poolT[r2][rr][((sl + rr) & 7)*8];
        acc[0][nt] = MFMA16(a0, bb, acc[0][nt], 0, 0, 0);
        acc[1][nt] = MFMA16(a1, bb, acc[1][nt], 0, 0, 0);
      }
    }
  }
  #pragma unroll
  for (int c2 = 0; c2 < 2; ++c2) {
    const int c4 = (cp*2 + c2)*16 + 4*lq;
    float s0 = bsc[c4], s1 = bsc[c4+1], s2 = bsc[c4+2], s3 = bsc[c4+3];
    float h0 = bsh[c4], h1 = bsh[c4+1], h2 = bsh[c4+2], h3 = bsh[c4+3];
    #pragma unroll
    for (int nt = 0; nt < 3; ++nt) {
      int s = nt*16 + lm;
      if (s < kS) {
        uint2 pk;
        pk.x = (unsigned)f2bu(fmaxf(acc[c2][nt][0]*s0 + h0, 0.f))
             | ((unsigned)f2bu(fmaxf(acc[c2][nt][1]*s1 + h1, 0.f)) << 16);
        pk.y = (unsigned)f2bu(fmaxf(acc[c2][nt][2]*s2 + h2, 0.f))
             | ((unsigned)f2bu(fmaxf(acc[c2][nt][3]*s3 + h3, 0.f)) << 16);
        *reinterpret_cast<uint2*>(&transOut[((size_t)(row0+r2)*kS + s)*kC + c4]) = pk;
      }
    }
  }
}

// ---- concat(trans[0..st]) -> conv1d(k9,pad4) via MFMA + BN + ReLU ; 2 rows/block ----
template<int NCI>
__global__ __launch_bounds__(256) void k_catconv(
    const bf16* __restrict__ t0, const bf16* __restrict__ t1, const bf16* __restrict__ t2,
    const bf16* __restrict__ wfrag,   // [9][NCI/32][4][64][8]
    const float* __restrict__ bnp, bf16* __restrict__ catOut)
{
  constexpr int CB = NCI/8;           // slots per row
  __shared__ __align__(16) bf16 poolT[2][56][NCI];
  __shared__ float bsc[kC], bsh[kC];
  const int tid = threadIdx.x;
  const int row0 = blockIdx.x * 2;
  if (tid < kC) {
    float g = bnp[tid], bb = bnp[kC + tid];
    float m = bnp[2*kC + tid], v = bnp[3*kC + tid];
    float sc = g / sqrtf(v + 1e-5f);
    bsc[tid] = sc; bsh[tid] = bb - m * sc;
  }
  unsigned int* pz = (unsigned int*)&poolT[0][0][0];
  for (int e = tid; e < 2*56*NCI/2; e += 256) pz[e] = 0u;
  __syncthreads();

  const bf16* tb[3] = {t0, t1, t2};
  for (int cc = tid; cc < 2*kS*CB; cc += 256) {
    int r2 = cc / (kS*CB), rem = cc % (kS*CB);
    int s = rem / CB, cb = rem % CB;
    int ch = cb * 8, i = ch >> 6, c = ch & 63;
    const short8v* src = (const short8v*)&tb[i][((size_t)(row0+r2)*kS + s)*kC + c];
    int lr = s + 4;
    int sl = (cb & ~7) | ((cb + lr) & 7);
    *(short8v*)&poolT[r2][lr][sl*8] = *src;
  }
  __syncthreads();

  const int wv = tid >> 6, lane = tid & 63;
  const int r2 = wv & 1, cp = wv >> 1;    // wave = (row, cout-pair)
  const int lm = lane & 15, lq = lane >> 4;
  float4v acc[2][3] = {{{0,0,0,0},{0,0,0,0},{0,0,0,0}},{{0,0,0,0},{0,0,0,0},{0,0,0,0}}};
  #pragma unroll
  for (int t = 0; t < 9; ++t) {
    #pragma unroll
    for (int chi = 0; chi < NCI/32; ++chi) {
      short8v a0 = *(const short8v*)&wfrag[(((t*(NCI/32) + chi)*4 + cp*2 + 0)*64 + lane)*8];
      short8v a1 = *(const short8v*)&wfrag[(((t*(NCI/32) + chi)*4 + cp*2 + 1)*64 + lane)*8];
      #pragma unroll
      for (int nt = 0; nt < 3; ++nt) {
        int rr = nt*16 + lm + t;
        int sl0 = chi*4 + lq;
        int sl = (sl0 & ~7) | ((sl0 + rr) & 7);
        short8v bb = *(const short8v*)&poolT[r2][rr][sl*8];
        acc[0][nt] = MFMA16(a0, bb, acc[0][nt], 0, 0, 0);
        acc[1][nt] = MFMA16(a1, bb, acc[1][nt], 0, 0, 0);
      }
    }
  }
  #pragma unroll
  for (int c2 = 0; c2 < 2; ++c2) {
    const int c4 = (cp*2 + c2)*16 + 4*lq;
    float s0 = bsc[c4], s1 = bsc[c4+1], s2 = bsc[c4+2], s3 = bsc[c4+3];
    float h0 = bsh[c4], h1 = bsh[c4+1], h2 = bsh[c4+2], h3 = bsh[c4+3];
    #pragma unroll
    for (int nt = 0; nt < 3; ++nt) {
      int s = nt*16 + lm;
      if (s < kS) {
        uint2 pk;
        pk.x = (unsigned)f2bu(fmaxf(acc[c2][nt][0]*s0 + h0, 0.f))
             | ((unsigned)f2bu(fmaxf(acc[c2][nt][1]*s1 + h1, 0.f)) << 16);
        pk.y = (unsigned)f2bu(fmaxf(acc[c2][nt][2]*s2 + h2, 0.f))
             | ((unsigned)f2bu(fmaxf(acc[c2][nt][3]*s3 + h3, 0.f)) << 16);
        *reinterpret_cast<uint2*>(&catOut[((size_t)(row0+r2)*kS + s)*kC + c4]) = pk;
      }
    }
  }
}

// ---- mega tail: fc+LN -> attn(QK^T, softmax, PV, residual) -> mlp+heads -> geometry/epi ----
__global__ __launch_bounds__(256) void k_tail(
    const bf16* __restrict__ catOut, const bf16* __restrict__ wfc,
    const float* __restrict__ fcb, const float* __restrict__ lng, const float* __restrict__ lnb,
    const bf16* __restrict__ key_pc, const bf16* __restrict__ val_ck,
    const float* __restrict__ fqw, const float* __restrict__ fqb,
    const float* __restrict__ aww, const float* __restrict__ awb,
    const bf16* __restrict__ mlpwT, const float* __restrict__ mlpb,
    const bf16* __restrict__ rcT, const float* __restrict__ rcb,
    const float* __restrict__ priors0, const float* __restrict__ priw_in, int stage,
    float* __restrict__ out, float* __restrict__ priw_out, float* __restrict__ pfeat_out)
{
  __shared__ __align__(16) float partS[4][16][68];  // fc partials, reused as S[16][264]
  __shared__ __align__(16) float roiL[12][68];
  __shared__ __align__(16) bf16 q[16][72];
  __shared__ __align__(16) bf16 P[16][264];
  __shared__ float rsum[16];
  __shared__ __align__(16) bf16 r2b[16][72];
  __shared__ __align__(16) bf16 h1l[16][72];
  __shared__ __align__(16) bf16 h2l[16][72];
  __shared__ float regc[12][84];
  __shared__ float ev[12][8];

  const int tid = threadIdx.x;
  const int blk = blockIdx.x, b = blk >> 4, tile = blk & 15;
  const int p0 = tile * 12;
  const int lane = tid & 63, wq = tid >> 6;
  const int lm = lane & 15, lq = lane >> 4;
  float (*S)[264] = (float (*)[264])&partS[0][0][0];

  { unsigned* z1 = (unsigned*)&q[0][0];
    for (int e = tid; e < 16*72/2; e += 256) z1[e] = 0u;
    unsigned* z2 = (unsigned*)&r2b[0][0];
    for (int e = tid; e < 16*72/2; e += 256) z2[e] = 0u; }

  {
    float4v fa[4] = {{0,0,0,0},{0,0,0,0},{0,0,0,0},{0,0,0,0}};
    int r0c = p0 + lm; if (r0c > p0 + 11) r0c = p0 + 11;
    const bf16* bb0 = catOut + (size_t)(b*kP + r0c) * 2304 + lq * 8;
    for (int kk = wq * 18; kk < wq * 18 + 18; ++kk) {
      short8v bf0 = *(const short8v*)&bb0[kk * 32];
      #pragma unroll
      for (int t = 0; t < 4; ++t) {
        short8v afrag = *(const short8v*)&wfc[((kk*4 + t)*64 + lane)*8];
        fa[t] = MFMA16(afrag, bf0, fa[t], 0, 0, 0);
      }
    }
    #pragma unroll
    for (int t = 0; t < 4; ++t)
      *(float4v*)&partS[wq][lm][t*16 + lq*4] = fa[t];
  }
  __syncthreads();
  for (int r = wq; r < 12; r += 4) {
    float v = partS[0][r][lane] + partS[1][r][lane] + partS[2][r][lane] + partS[3][r][lane]
            + fcb[lane];
    float s1 = v, s2 = v * v;
    #pragma unroll
    for (int m = 32; m; m >>= 1) { s1 += __shfl_xor(s1, m, 64); s2 += __shfl_xor(s2, m, 64); }
    float mu = s1 * (1.f/64.f);
    float var = s2 * (1.f/64.f) - mu * mu;
    float y = fmaxf((v - mu) * rsqrtf(var + 1e-5f) * lng[lane] + lnb[lane], 0.f);
    roiL[r][lane] = y;
    int p = p0 + r;
    q[r][lane] = __float2bfloat16(fmaxf(y * fqw[p] + fqb[p], 0.f));
  }
  __syncthreads();

  {
    float4v acc[4] = {{0,0,0,0},{0,0,0,0},{0,0,0,0},{0,0,0,0}};
    #pragma unroll
    for (int ks = 0; ks < 2; ++ks) {
      short8v aq0 = *(const short8v*)&q[lm][ks*32 + 8*lq];
      #pragma unroll
      for (int nt = 0; nt < 4; ++nt) {
        int pos = (wq*4 + nt)*16 + lm;
        short8v bk = *(const short8v*)&key_pc[((size_t)(b*256 + pos))*kC + ks*32 + 8*lq];
        acc[nt] = MFMA16(aq0, bk, acc[nt], 0, 0, 0);
      }
    }
    #pragma unroll
    for (int nt = 0; nt < 4; ++nt)
      #pragma unroll
      for (int r = 0; r < 4; ++r)
        S[lq*4 + r][(wq*4 + nt)*16 + lm] = acc[nt][r] * 0.125f;
  }
  __syncthreads();

  {
    int r = tid >> 4, g = tid & 15;
    float mx = -1e30f;
    #pragma unroll 16
    for (int k = 0; k < 16; ++k) { int c = g + 16*k; if (c < 250) mx = fmaxf(mx, S[r][c]); }
    #pragma unroll
    for (int m = 1; m < 16; m <<= 1) mx = fmaxf(mx, __shfl_xor(mx, m, 64));
    float sum = 0.f;
    #pragma unroll 16
    for (int k = 0; k < 16; ++k) {
      int c = g + 16*k;
      float e = 0.f;
      if (c < 250) { e = expf(S[r][c] - mx); sum += e; }
      P[r][c] = __float2bfloat16(e);
    }
    #pragma unroll
    for (int m = 1; m < 16; m <<= 1) sum += __shfl_xor(sum, m, 64);
    if (g == 0) rsum[r] = sum;
  }
  __syncthreads();

  {
    float4v acc = {0,0,0,0};
    #pragma unroll
    for (int ks = 0; ks < 8; ++ks) {
      short8v bv = *(const short8v*)&val_ck[((size_t)(b*kC + wq*16 + lm))*256 + ks*32 + 8*lq];
      short8v ap0 = *(const short8v*)&P[lm][ks*32 + 8*lq];
      acc = MFMA16(ap0, bv, acc, 0, 0, 0);
    }
    #pragma unroll
    for (int r = 0; r < 4; ++r) {
      int pl = lq*4 + r;
      if (pl < 12) {
        int p = p0 + pl, c = wq*16 + lm;
        float ctx = acc[r] / rsum[pl];
        r2b[pl][c] = __float2bfloat16(roiL[pl][c] + ctx * aww[p] + awb[p]);
      }
    }
  }
  __syncthreads();

  {
    float4v acc = {0,0,0,0};
    #pragma unroll
    for (int ks = 0; ks < 2; ++ks) {
      short8v a0 = *(const short8v*)&r2b[lm][ks*32 + 8*lq];
      short8v bw = *(const short8v*)&mlpwT[(wq*16 + lm)*kC + ks*32 + 8*lq];
      acc = MFMA16(a0, bw, acc, 0, 0, 0);
    }
    #pragma unroll
    for (int r = 0; r < 4; ++r) {
      int rw = lq*4 + r, col = wq*16 + lm;
      h1l[rw][col] = __float2bfloat16(fmaxf(acc[r] + mlpb[col], 0.f));
    }
  }
  __syncthreads();
  {
    float4v acc = {0,0,0,0};
    #pragma unroll
    for (int ks = 0; ks < 2; ++ks) {
      short8v a0 = *(const short8v*)&h1l[lm][ks*32 + 8*lq];
      short8v bw = *(const short8v*)&mlpwT[(wq*16 + lm)*kC + ks*32 + 8*lq];
      acc = MFMA16(a0, bw, acc, 0, 0, 0);
    }
    #pragma unroll
    for (int r = 0; r < 4; ++r) {
      int rw = lq*4 + r, col = wq*16 + lm;
      h2l[rw][col] = __float2bfloat16(fmaxf(acc[r] + mlpb[col], 0.f));
    }
  }
  __syncthreads();
  for (int ntile = wq; ntile < 5; ntile += 4) {
    float4v acc = {0,0,0,0};
    #pragma unroll
    for (int ks = 0; ks < 2; ++ks) {
      short8v a0 = *(const short8v*)&h2l[lm][ks*32 + 8*lq];
      short8v bw = *(const short8v*)&rcT[(ntile*16 + lm)*kC + ks*32 + 8*lq];
      acc = MFMA16(a0, bw, acc, 0, 0, 0);
    }
    #pragma unroll
    for (int r = 0; r < 4; ++r) {
      int rw = lq*4 + r, col = ntile*16 + lm;
      if (rw < 12) regc[rw][col] = acc[r] + rcb[col];
    }
  }
  __syncthreads();

  if (tid < 12) {
    int r = tid, p = p0 + r, grow = b*kP + p;
    float pr2, pr3, pr4;
    if (stage == 0) {
      pr2 = priors0[p*78 + 2]; pr3 = priors0[p*78 + 3]; pr4 = priors0[p*78 + 4];
    } else {
      const float* pw = priw_in + (size_t)grow * 78;
      pr2 = pw[2]; pr3 = pw[3]; pr4 = pw[4];
    }
    float p2 = pr2 + regc[r][0], p3 = pr3 + regc[r][1];
    float p4 = pr4 + regc[r][2], p5 = regc[r][3];
    ev[r][0] = p2; ev[r][1] = p3; ev[r][2] = p4; ev[r][3] = p5;
    ev[r][4] = 320.f / tanf(p4 * kPI + 1e-5f);
    ev[r][5] = regc[r][76]; ev[r][6] = regc[r][77];
  }
  __syncthreads();
  for (int e = tid; e < 12*78; e += 256) {
    int r = e / 78, o = e % 78;
    int p = p0 + r, grow = b*kP + p;
    float p2 = ev[r][0], p3 = ev[r][1], t320 = ev[r][4];
    float g = 0.f, v;
    if (o >= 6) g = (p3 * 799.f + ((float)(o-6) / 71.f - p2) * t320) / 799.f;
    if      (o == 0) v = ev[r][5];
    else if (o == 1) v = ev[r][6];
    else if (o == 2) v = p2;
    else if (o == 3) v = p3;
    else if (o == 4) v = ev[r][2];
    else if (o == 5) v = ev[r][3];
    else             v = g + regc[r][4 + (o - 6)];
    out[((size_t)(stage*kB + b)*kP + p) * 78 + o] = v;
    if (stage < 2) priw_out[(size_t)grow*78 + o] = (o < 6) ? v : g;
  }
  if (stage < 2) {
    for (int e = tid; e < 12*kS; e += 256) {
      int r = e / kS, si = e % kS;
      int grow = b*kP + p0 + r;
      float p2 = ev[r][0], p3 = ev[r][1], t320 = ev[r][4];
      pfeat_out[(size_t)grow*kS + si] =
          (p3 * 799.f + ((float)d_SX[si] / 71.f - p2) * t320) / 799.f;
    }
  }
}

extern "C" void kernel_launch(void* const* d_in, const int* in_sizes, int n_in,
                              void* d_out, int out_size, void* d_ws, size_t ws_size,
                              hipStream_t stream) {
  const float* x0      = (const float*)d_in[0];
  const float* x1      = (const float*)d_in[1];
  const float* x2      = (const float*)d_in[2];
  const float* priors0 = (const float*)d_in[3];
  const float* pfeat0  = (const float*)d_in[4];
  const float* conv_w  = (const float*)d_in[5];
  const float* bn_conv = (const float*)d_in[6];
  const float* cat_w[3]= {(const float*)d_in[7], (const float*)d_in[8], (const float*)d_in[9]};
  const float* bn_cat  = (const float*)d_in[10];
  const float* fkey_w  = (const float*)d_in[11];
  const float* bn_key  = (const float*)d_in[12];
  const float* fval_w  = (const float*)d_in[13];
  const float* fval_b  = (const float*)d_in[14];
  const float* fq_w    = (const float*)d_in[15];
  const float* fq_b    = (const float*)d_in[16];
  const float* attnW_w = (const float*)d_in[17];
  const float* attnW_b = (const float*)d_in[18];
  const float* fc_w    = (const float*)d_in[19];
  const float* fc_b    = (const float*)d_in[20];
  const float* ln_g    = (const float*)d_in[21];
  const float* ln_b    = (const float*)d_in[22];
  const float* mlp_w   = (const float*)d_in[23];
  const float* mlp_b   = (const float*)d_in[24];
  const float* reg_w   = (const float*)d_in[25];
  const float* reg_b   = (const float*)d_in[26];
  const float* cls_w   = (const float*)d_in[27];
  const float* cls_b   = (const float*)d_in[28];
  float* out = (float*)d_out;

  char* ws = (char*)d_ws;
  size_t off = 0;
  auto alloc = [&](size_t bytes) { void* pp = ws + off; off += (bytes + 255) & ~(size_t)255; return pp; };
  bf16* trans[3];
  for (int i = 0; i < 3; ++i) trans[i] = (bf16*)alloc((size_t)kRows * 2304 * sizeof(bf16));
  bf16*  catout = (bf16*) alloc((size_t)kRows * 2304 * sizeof(bf16));
  bf16*  key_pc[3]; bf16* val_ck[3];
  for (int i = 0; i < 3; ++i) {
    key_pc[i] = (bf16*)alloc((size_t)kB * 256 * kC * sizeof(bf16));
    val_ck[i] = (bf16*)alloc((size_t)kB * kC * 256 * sizeof(bf16));
  }
  float* priwA  = (float*)alloc((size_t)kRows * 78 * sizeof(float));
  float* priwB  = (float*)alloc((size_t)kRows * 78 * sizeof(float));
  float* pfw    = (float*)alloc((size_t)kRows * kS * sizeof(float));
  bf16* wtr[3], *wcat[3];
  const int catCI[3] = {64, 128, 192};
  for (int i = 0; i < 3; ++i) wtr[i]  = (bf16*)alloc((size_t)64*64*9 * sizeof(bf16));
  for (int i = 0; i < 3; ++i) wcat[i] = (bf16*)alloc((size_t)64*catCI[i]*9 * sizeof(bf16));
  bf16* wfc    = (bf16*)alloc((size_t)2304*64 * sizeof(bf16));
  bf16* mlpwT  = (bf16*)alloc((size_t)64*64 * sizeof(bf16));
  bf16* rcT    = (bf16*)alloc((size_t)80*64 * sizeof(bf16));
  float* rcb   = (float*)alloc((size_t)80 * sizeof(float));
  float* fkeyT = (float*)alloc((size_t)64*64 * sizeof(float));
  float* fvalT = (float*)alloc((size_t)64*64 * sizeof(float));
  const int hd[3] = {10, 20, 40}, wd[3] = {25, 50, 100};
  bf16* fmapT[3];
  for (int i = 0; i < 3; ++i)
    fmapT[i] = (bf16*)alloc((size_t)kB * hd[i] * wd[i] * kC * sizeof(bf16));
  (void)ws_size; (void)in_sizes; (void)n_in; (void)out_size;

  // merged one-time preps: 3 dispatches
  k_prep_all<<<(496640 + 255)/256, 256, 0, stream>>>(
      conv_w, cat_w[0], cat_w[1], cat_w[2], fc_w, mlp_w, reg_w, reg_b, cls_w, cls_b,
      fkey_w, fval_w,
      wtr[0], wtr[1], wtr[2], wcat[0], wcat[1], wcat[2], wfc, mlpwT, rcT, rcb,
      fkeyT, fvalT);
  k_transpose3<<<kB*70, 256, 0, stream>>>(x2, x1, x0, fmapT[0], fmapT[1], fmapT[2]);
  k_keyval3<<<3*kB*64, 256, 0, stream>>>(fmapT[0], fmapT[1], fmapT[2],
                                         fkeyT, bn_key, fvalT, fval_b,
                                         key_pc[0], val_ck[0], key_pc[1], val_ck[1],
                                         key_pc[2], val_ck[2]);

  for (int st = 0; st < 3; ++st) {
    const int h = hd[st], w = wd[st];
    const float* priw_in  = (st == 1) ? priwA : priwB;   // unused at st==0
    float*       priw_out = (st == 0) ? priwA : priwB;   // ping-pong
    k_trans<<<kRows/2, 256, 0, stream>>>(fmapT[st], h, w, pfeat0, pfw, st,
                                         wtr[st], bn_conv + st*4*kC, trans[st]);
    if (st == 0)
      k_catconv<64><<<kRows/2, 256, 0, stream>>>(trans[0], trans[1], trans[2], wcat[0],
                                                 bn_cat + st*4*kC, catout);
    else if (st == 1)
      k_catconv<128><<<kRows/2, 256, 0, stream>>>(trans[0], trans[1], trans[2], wcat[1],
                                                  bn_cat + st*4*kC, catout);
    else
      k_catconv<192><<<kRows/2, 256, 0, stream>>>(trans[0], trans[1], trans[2], wcat[2],
                                                  bn_cat + st*4*kC, catout);
    k_tail<<<kB*16, 256, 0, stream>>>(catout, wfc, fc_b, ln_g, ln_b,
                                      key_pc[st], val_ck[st], fq_w, fq_b, attnW_w, attnW_b,
                                      mlpwT, mlp_b, rcT, rcb,
                                      priors0, priw_in, st, out, priw_out, pfw);
  }
}